// Round 13
// baseline (332.915 us; speedup 1.0000x reference)
//
#include <hip/hip_runtime.h>

#define DEV __device__ __forceinline__

typedef short short4v __attribute__((ext_vector_type(4)));
typedef short short8v __attribute__((ext_vector_type(8)));
typedef float float4v __attribute__((ext_vector_type(4)));
typedef unsigned short u16;

#define S32E ((size_t)65536 * 32)   // head stride, elements (u16)
#define S64B ((size_t)65536 * 64)   // head stride, bytes

DEV unsigned short f2bf(float f) {
  unsigned u = __builtin_bit_cast(unsigned, f);
  u += 0x7fffu + ((u >> 16) & 1u);
  return (unsigned short)(u >> 16);
}
DEV float bf2f(unsigned short h) {
  unsigned u = ((unsigned)h) << 16;
  return __builtin_bit_cast(float, u);
}
DEV float4v mfma32(short8v a, short8v b, float4v c) {
  return __builtin_amdgcn_mfma_f32_16x16x32_bf16(a, b, c, 0, 0, 0);
}
DEV float4v mfma16(short4v a, short4v b, float4v c) {
  return __builtin_amdgcn_mfma_f32_16x16x16bf16_1k(a, b, c, 0, 0, 0);
}
DEV void async16(const void* g, void* l) {
  __builtin_amdgcn_global_load_lds(
      (const __attribute__((address_space(1))) unsigned*)g,
      (__attribute__((address_space(3))) unsigned*)l, 16, 0, 0);
}
DEV short4v cvt4(float4v v) {
  short4v r;
  r[0] = (short)f2bf(v[0]); r[1] = (short)f2bf(v[1]);
  r[2] = (short)f2bf(v[2]); r[3] = (short)f2bf(v[3]);
  return r;
}
DEV short8v cvt8(float4v a, float4v b) {
  short8v o;
  o[0] = (short)f2bf(a[0]); o[1] = (short)f2bf(a[1]);
  o[2] = (short)f2bf(a[2]); o[3] = (short)f2bf(a[3]);
  o[4] = (short)f2bf(b[0]); o[5] = (short)f2bf(b[1]);
  o[6] = (short)f2bf(b[2]); o[7] = (short)f2bf(b[3]);
  return o;
}

// ------------- weight convert + transpose (LDS-tiled, coalesced) -------------
__global__ __launch_bounds__(256)
void cvt_wT(const float* Wq, const float* Wk, const float* Wv, const float* Wo,
            const float* W1, const float* W2,
            u16* Wqt, u16* Wkt, u16* Wvt, u16* Wot, u16* W1t, u16* W2t) {
  __shared__ float ld[64 * 69];
  const float* src; u16* dst; int R, C; bool permk = false;
  switch (blockIdx.y) {
    case 0: src = Wq; dst = Wqt; R = 256;  C = 256;  break;
    case 1: src = Wk; dst = Wkt; R = 256;  C = 256;  break;
    case 2: src = Wv; dst = Wvt; R = 256;  C = 256;  break;
    case 3: src = Wo; dst = Wot; R = 256;  C = 256;  break;
    case 4: src = W1; dst = W1t; R = 256;  C = 1024; break;
    default: src = W2; dst = W2t; R = 1024; C = 256; permk = true; break;
  }
  const int ntile = (R >> 6) * (C >> 6);
  if ((int)blockIdx.x >= ntile) return;
  const int tf = blockIdx.x % (R >> 6);
  const int tn = blockIdx.x / (R >> 6);
  const int r0 = tf << 6, c0 = tn << 6;
  const int tid = threadIdx.x;
  {
    int lr = tid >> 4, lc = (tid & 15) << 2;
    #pragma unroll
    for (int ps = 0; ps < 4; ++ps) {
      int r = ps * 16 + lr;
      float4v v = *(const float4v*)(src + (size_t)(r0 + r) * C + c0 + lc);
      #pragma unroll
      for (int e = 0; e < 4; ++e) ld[r * 69 + lc + e] = v[e];
    }
  }
  __syncthreads();
  {
    int p8 = (tid & 7) << 3;
    #pragma unroll
    for (int ps = 0; ps < 2; ++ps) {
      int n = ps * 32 + (tid >> 3);
      short8v o;
      #pragma unroll
      for (int e = 0; e < 8; ++e) {
        int p = p8 + e;
        int fl = p;
        if (permk) {
          int m = p & 31;
          fl = (p & 32) + 16 * ((m >> 2) & 1) + 4 * (m >> 3) + (m & 3);
        }
        o[e] = (short)f2bf(ld[fl * 69 + n]);
      }
      *(short8v*)(dst + (size_t)(c0 + n) * R + r0 + p8) = o;
    }
  }
}

// ---------------- Q projection GEMM: out = A_f32 @ Wt^T + bias, head-major out ----
__global__ __launch_bounds__(256, 2)
void gemm_q(const float* __restrict__ A, const u16* __restrict__ Wt,
            const float* __restrict__ bias, u16* __restrict__ out) {
  __shared__ alignas(16) char sm[32768];
  char* sa = sm;
  char* sb = sm + 16384;
  const int tid = threadIdx.x;
  const int w = tid >> 6, lane = tid & 63;
  const int ln15 = lane & 15, gq = lane >> 4;
  const int wr = w >> 1, wc = w & 1;
  const int m0 = blockIdx.x * 128, n0 = blockIdx.y * 128;
  const char* Wb = (const char*)Wt;

  float4v acc[4][4] = {};
  for (int kk = 0; kk < 4; ++kk) {
    #pragma unroll
    for (int p = 0; p < 4; ++p) {
      int L = p * 4096 + w * 1024 + lane * 16;
      int row = L >> 7, colb = L & 127;
      const float* src = A + (size_t)(m0 + row) * 256 + kk * 64 + (colb >> 1);
      float4v f0 = *(const float4v*)(src);
      float4v f1 = *(const float4v*)(src + 4);
      *(short8v*)(sa + row * 128 + (colb ^ ((row & 7) << 4))) = cvt8(f0, f1);
    }
    #pragma unroll
    for (int p = 0; p < 4; ++p) {
      int L = p * 4096 + w * 1024 + lane * 16;
      int row = L >> 7, colb = L & 127;
      int sw = colb ^ ((row & 7) << 4);
      async16(Wb + (size_t)(n0 + row) * 512 + kk * 128 + sw, sb + p * 4096 + w * 1024);
    }
    __syncthreads();
    #pragma unroll
    for (int ks = 0; ks < 2; ++ks) {
      short8v af[4], bfr[4];
      #pragma unroll
      for (int mf = 0; mf < 4; ++mf) {
        int r = wr * 64 + mf * 16 + ln15;
        af[mf] = *(const short8v*)(sa + r * 128 + ((ks * 64 + gq * 16) ^ ((r & 7) << 4)));
      }
      #pragma unroll
      for (int nf = 0; nf < 4; ++nf) {
        int r = wc * 64 + nf * 16 + ln15;
        bfr[nf] = *(const short8v*)(sb + r * 128 + ((ks * 64 + gq * 16) ^ ((r & 7) << 4)));
      }
      #pragma unroll
      for (int mf = 0; mf < 4; ++mf)
        #pragma unroll
        for (int nf = 0; nf < 4; ++nf)
          acc[mf][nf] = mfma32(af[mf], bfr[nf], acc[mf][nf]);
    }
    __syncthreads();
  }
  #pragma unroll
  for (int nf = 0; nf < 4; ++nf) {
    int col = n0 + wc * 64 + nf * 16 + ln15;
    float bb = bias[col];
    #pragma unroll
    for (int mf = 0; mf < 4; ++mf) {
      int rb = m0 + wr * 64 + mf * 16 + 4 * gq;
      #pragma unroll
      for (int j = 0; j < 4; ++j) {
        float v = acc[mf][nf][j] + bb;
        out[(size_t)(col >> 5) * S32E + (size_t)(rb + j) * 32 + (col & 31)] = f2bf(v);
      }
    }
  }
}

// ---------------- merged K/V projection GEMM (f32 A, head-major outputs) ----------------
__global__ __launch_bounds__(256, 2)
void gemm_kv(const float* __restrict__ A, const u16* __restrict__ Wt,
             const float* __restrict__ bk, const float* __restrict__ bv,
             u16* __restrict__ Kout, u16* __restrict__ Vout) {
  __shared__ alignas(16) char sm[32768];
  char* sa = sm;
  char* sb = sm + 16384;
  const int tid = threadIdx.x;
  const int w = tid >> 6, lane = tid & 63;
  const int ln15 = lane & 15, gq = lane >> 4;
  const int wr = w >> 1, wc = w & 1;
  const int m0 = blockIdx.x * 128, n0 = blockIdx.y * 128;
  const char* Wb = (const char*)Wt;

  float4v acc[4][4] = {};
  for (int kk = 0; kk < 4; ++kk) {
    #pragma unroll
    for (int p = 0; p < 4; ++p) {
      int L = p * 4096 + w * 1024 + lane * 16;
      int row = L >> 7, colb = L & 127;
      const float* src = A + (size_t)(m0 + row) * 256 + kk * 64 + (colb >> 1);
      float4v f0 = *(const float4v*)(src);
      float4v f1 = *(const float4v*)(src + 4);
      *(short8v*)(sa + row * 128 + (colb ^ ((row & 7) << 4))) = cvt8(f0, f1);
    }
    #pragma unroll
    for (int p = 0; p < 4; ++p) {
      int L = p * 4096 + w * 1024 + lane * 16;
      int row = L >> 7, colb = L & 127;
      int sw = colb ^ ((row & 7) << 4);
      async16(Wb + (size_t)(n0 + row) * 512 + kk * 128 + sw, sb + p * 4096 + w * 1024);
    }
    __syncthreads();
    #pragma unroll
    for (int ks = 0; ks < 2; ++ks) {
      short8v af[4], bfr[4];
      #pragma unroll
      for (int mf = 0; mf < 4; ++mf) {
        int r = wr * 64 + mf * 16 + ln15;
        af[mf] = *(const short8v*)(sa + r * 128 + ((ks * 64 + gq * 16) ^ ((r & 7) << 4)));
      }
      #pragma unroll
      for (int nf = 0; nf < 4; ++nf) {
        int r = wc * 64 + nf * 16 + ln15;
        bfr[nf] = *(const short8v*)(sb + r * 128 + ((ks * 64 + gq * 16) ^ ((r & 7) << 4)));
      }
      #pragma unroll
      for (int mf = 0; mf < 4; ++mf)
        #pragma unroll
        for (int nf = 0; nf < 4; ++nf)
          acc[mf][nf] = mfma32(af[mf], bfr[nf], acc[mf][nf]);
    }
    __syncthreads();
  }
  #pragma unroll
  for (int nf = 0; nf < 4; ++nf) {
    int col = n0 + wc * 64 + nf * 16 + ln15;  // 0..511
    const bool isK = col < 256;
    const int c2 = col & 255;
    u16* outp = isK ? Kout : Vout;
    float bb = isK ? bk[c2] : bv[c2];
    const size_t hb = (size_t)(c2 >> 5) * S32E;
    const int d = c2 & 31;
    #pragma unroll
    for (int mf = 0; mf < 4; ++mf) {
      int rb = m0 + wr * 64 + mf * 16 + 4 * gq;
      #pragma unroll
      for (int j = 0; j < 4; ++j)
        outp[hb + (size_t)(rb + j) * 32 + d] = f2bf(acc[mf][nf][j] + bb);
    }
  }
}

// ---- Wo GEMM + residual + LN1 fused: x = LN1(q_in + ctx@Wo + bo), bf16 out ----
__global__ __launch_bounds__(256, 2)
void gemm_wo_ln(const u16* __restrict__ A, const u16* __restrict__ Wt,
                const float* __restrict__ bias, const float* __restrict__ resid,
                const float* __restrict__ lng, const float* __restrict__ lnb,
                u16* __restrict__ xout) {
  __shared__ alignas(16) char sa[16384];   // A tile [128][128B], XOR-swizzled
  __shared__ alignas(16) char sb[32768];   // B tile [256][128B], XOR-swizzled
  __shared__ float red[512];               // [128 rows][2 wc][2 {sum,sq}]
  const int tid = threadIdx.x;
  const int w = tid >> 6, lane = tid & 63;
  const int ln15 = lane & 15, gq = lane >> 4;
  const int wr = w >> 1, wc = w & 1;
  const int m0 = blockIdx.x * 128;
  const char* Ab = (const char*)A;
  const char* Wb = (const char*)Wt;

  float4v acc[4][8] = {};
  for (int kk = 0; kk < 4; ++kk) {
    #pragma unroll
    for (int p = 0; p < 4; ++p) {
      int L = p * 4096 + tid * 16;
      int row = L >> 7, colb = L & 127;
      int sw = colb ^ ((row & 7) << 4);
      int b = kk * 128 + sw;
      async16(Ab + (size_t)(b >> 6) * S64B + (size_t)(m0 + row) * 64 + (b & 63),
              sa + L);
    }
    #pragma unroll
    for (int p = 0; p < 8; ++p) {
      int L = p * 4096 + tid * 16;
      int row = L >> 7, colb = L & 127;
      int sw = colb ^ ((row & 7) << 4);
      async16(Wb + (size_t)row * 512 + kk * 128 + sw, sb + L);
    }
    __syncthreads();
    #pragma unroll
    for (int ks = 0; ks < 2; ++ks) {
      short8v af[4], bfr[8];
      #pragma unroll
      for (int mf = 0; mf < 4; ++mf) {
        int r = wr * 64 + mf * 16 + ln15;
        af[mf] = *(const short8v*)(sa + r * 128 + ((ks * 64 + gq * 16) ^ ((r & 7) << 4)));
      }
      #pragma unroll
      for (int nf = 0; nf < 8; ++nf) {
        int r = wc * 128 + nf * 16 + ln15;
        bfr[nf] = *(const short8v*)(sb + r * 128 + ((ks * 64 + gq * 16) ^ ((r & 7) << 4)));
      }
      #pragma unroll
      for (int mf = 0; mf < 4; ++mf)
        #pragma unroll
        for (int nf = 0; nf < 8; ++nf)
          acc[mf][nf] = mfma32(af[mf], bfr[nf], acc[mf][nf]);
    }
    __syncthreads();
  }

  #pragma unroll
  for (int mf = 0; mf < 4; ++mf)
    #pragma unroll
    for (int j = 0; j < 4; ++j) {
      int lr = wr * 64 + mf * 16 + 4 * gq + j;   // local row 0..127
      int r2 = m0 + lr;
      float sum = 0.f, sq = 0.f;
      #pragma unroll
      for (int nf = 0; nf < 8; ++nf) {
        int col = wc * 128 + nf * 16 + ln15;
        float v = acc[mf][nf][j] + bias[col] + resid[(size_t)r2 * 256 + col];
        acc[mf][nf][j] = v;
        sum += v;
        sq += v * v;
      }
      #pragma unroll
      for (int m = 1; m <= 8; m <<= 1) {
        sum += __shfl_xor(sum, m);
        sq += __shfl_xor(sq, m);
      }
      if (ln15 == 0) {
        red[lr * 4 + wc * 2] = sum;
        red[lr * 4 + wc * 2 + 1] = sq;
      }
    }
  __syncthreads();

  #pragma unroll
  for (int mf = 0; mf < 4; ++mf)
    #pragma unroll
    for (int j = 0; j < 4; ++j) {
      int lr = wr * 64 + mf * 16 + 4 * gq + j;
      int r2 = m0 + lr;
      float S = red[lr * 4] + red[lr * 4 + 2];
      float S2 = red[lr * 4 + 1] + red[lr * 4 + 3];
      float mu = S * (1.f / 256.f);
      float var = S2 * (1.f / 256.f) - mu * mu;
      float rstd = rsqrtf(var + 1e-5f);
      #pragma unroll
      for (int nf = 0; nf < 8; ++nf) {
        int col = wc * 128 + nf * 16 + ln15;
        float o = (acc[mf][nf][j] - mu) * rstd * lng[col] + lnb[col];
        xout[(size_t)r2 * 256 + col] = f2bf(o);
      }
    }
}

// ---------------- windowed attention v2: one block per (window, head) ----------------
__global__ __launch_bounds__(256, 2)
void attn_v2(const u16* __restrict__ Qg, const u16* __restrict__ Kg,
             const u16* __restrict__ Vg, u16* __restrict__ ctx) {
  __shared__ alignas(16) char ks[256 * 80];
  __shared__ alignas(16) char vs[256 * 80];
  const int bw = blockIdx.x;
  const int win = bw >> 3, head = bw & 7;
  const int tid = threadIdx.x;
  const int w = tid >> 6, lane = tid & 63;
  const int ln15 = lane & 15, gq = lane >> 4;
  const int tok0 = win << 8;
  const u16* Qh = Qg + head * S32E + (size_t)tok0 * 32;
  const u16* Kh = Kg + head * S32E + (size_t)tok0 * 32;
  const u16* Vh = Vg + head * S32E + (size_t)tok0 * 32;
  u16* Ch = ctx + head * S32E + (size_t)tok0 * 32;

  #pragma unroll
  for (int i = 0; i < 4; ++i) {
    int L = i * 4096 + tid * 16;
    int row = L >> 6, colb = L & 63;
    short8v kv0 = *(const short8v*)((const char*)Kh + L);
    short8v vv0 = *(const short8v*)((const char*)Vh + L);
    *(short8v*)(ks + row * 80 + colb) = kv0;
    *(short8v*)(vs + row * 80 + colb) = vv0;
  }
  __syncthreads();

  const float KSC = (float)(1.4426950408889634 / 5.656854249492381);  // log2e/sqrt(32)

  for (int pass = 0; pass < 2; ++pass) {
    const int q0 = w * 64 + pass * 32;

    short8v qf[2];
    #pragma unroll
    for (int qi = 0; qi < 2; ++qi)
      qf[qi] = *(const short8v*)(Qh + (size_t)(q0 + qi * 16 + ln15) * 32 + gq * 8);

    float4v s[16][2];
    #pragma unroll
    for (int kf = 0; kf < 16; ++kf) {
      short8v kfr = *(const short8v*)(ks + (16 * kf + ln15) * 80 + gq * 16);
      float4v z = {0.f, 0.f, 0.f, 0.f};
      s[kf][0] = mfma32(kfr, qf[0], z);
      s[kf][1] = mfma32(kfr, qf[1], z);
    }

    float rs[2];
    #pragma unroll
    for (int qi = 0; qi < 2; ++qi) {
      float mx = -1e30f;
      #pragma unroll
      for (int kf = 0; kf < 16; ++kf)
        #pragma unroll
        for (int j = 0; j < 4; ++j) mx = fmaxf(mx, s[kf][qi][j]);
      mx = fmaxf(mx, __shfl_xor(mx, 16));
      mx = fmaxf(mx, __shfl_xor(mx, 32));
      float mk = mx * KSC;
      float sum = 0.f;
      #pragma unroll
      for (int kf = 0; kf < 16; ++kf)
        #pragma unroll
        for (int j = 0; j < 4; ++j) {
          float p = exp2f(fmaf(s[kf][qi][j], KSC, -mk));
          s[kf][qi][j] = p;
          sum += p;
        }
      sum += __shfl_xor(sum, 16);
      sum += __shfl_xor(sum, 32);
      rs[qi] = 1.0f / sum;
    }

    float4v cacc[2][2] = {};  // [df][qi]
    #pragma unroll
    for (int kss = 0; kss < 16; ++kss) {
      short4v pb[2];
      pb[0] = cvt4(s[kss][0]);
      pb[1] = cvt4(s[kss][1]);
      #pragma unroll
      for (int df = 0; df < 2; ++df) {
        const char* vb = vs + (size_t)(16 * kss + 4 * gq) * 80 + (df * 16 + ln15) * 2;
        short4v va;
        va[0] = *(const short*)(vb);
        va[1] = *(const short*)(vb + 80);
        va[2] = *(const short*)(vb + 160);
        va[3] = *(const short*)(vb + 240);
        cacc[df][0] = mfma16(va, pb[0], cacc[df][0]);
        cacc[df][1] = mfma16(va, pb[1], cacc[df][1]);
      }
    }

    #pragma unroll
    for (int qi = 0; qi < 2; ++qi)
      #pragma unroll
      for (int df = 0; df < 2; ++df) {
        short4v o;
        #pragma unroll
        for (int j = 0; j < 4; ++j) o[j] = (short)f2bf(cacc[df][qi][j] * rs[qi]);
        *(short4v*)(Ch + (size_t)(q0 + qi * 16 + ln15) * 32 + df * 16 + 4 * gq) = o;
      }
  }
}

// ---------------- fused FFN v9: v6 template with CHUNK=64 (params-only change) ----
// out = LN2(x + relu(x@W1+b1)@W2 + b2). 512 threads, 256 rows/block, wave owns
// 32 rows; 16 chunks of 64 f (vs v6's 32 of 32) -> barrier count halved.
// w1c [64][512B] x2, w2c [256][144B] x2 (128B data + 16 pad; slot-uniform),
// same sigma k-perm (acts per-32-block; both halves of the 64-chunk covered).
__global__ __launch_bounds__(512, 1)
void ffn_v9(const u16* __restrict__ X, const u16* __restrict__ W1t,
            const u16* __restrict__ W2tp, const float* __restrict__ b1,
            const float* __restrict__ b2, const float* __restrict__ g2,
            const float* __restrict__ be2, float* __restrict__ out) {
  __shared__ alignas(16) char w1c[2][32768];   // [64 f][512B k], XOR-swizzled
  __shared__ alignas(16) char w2c[2][36864];   // [256 n][144B] (128B data + 16 pad)
  __shared__ alignas(16) float b1s[1024];
  const int tid = threadIdx.x;  // 0..511
  const int w = tid >> 6, lane = tid & 63;
  const int ln15 = lane & 15, gq = lane >> 4;
  const int m0 = blockIdx.x * 256;
  const int wrow0 = m0 + w * 32;

  b1s[tid] = b1[tid];
  b1s[tid + 512] = b1[tid + 512];

  short8v xr[2][8];
  #pragma unroll
  for (int ct = 0; ct < 2; ++ct)
    #pragma unroll
    for (int kc = 0; kc < 8; ++kc)
      xr[ct][kc] = *(const short8v*)(X + (size_t)(wrow0 + ct * 16 + ln15) * 256 + kc * 32 + gq * 8);

  float4v ff[2][16] = {};
  short8v w2r[4];

  const char* W1b = (const char*)W1t;
  const char* W2b = (const char*)W2tp;

  // ---- staging helpers (c = chunk index 0..15); 512 threads -> 4 x 16B each ----
  #define STAGE_W1(buf, c)                                                     \
    {                                                                          \
      _Pragma("unroll")                                                        \
      for (int p = 0; p < 4; ++p) {                                            \
        int L = p * 8192 + tid * 16;                                           \
        int r = L >> 9, colb = L & 511;                                        \
        async16(W1b + (size_t)((c) * 64 + r) * 512 + (colb ^ ((r & 7) << 4)),  \
                w1c[buf] + L);                                                 \
      }                                                                        \
    }
  #define LOAD_W2(c)                                                           \
    {                                                                          \
      _Pragma("unroll")                                                        \
      for (int p = 0; p < 4; ++p) {                                            \
        int idx = p * 8192 + tid * 16;                                         \
        int n = idx >> 7, off = idx & 127;                                     \
        w2r[p] = *(const short8v*)(W2b + (size_t)n * 2048 + (c) * 128 + off);  \
      }                                                                        \
    }
  #define WRITE_W2(buf)                                                        \
    {                                                                          \
      _Pragma("unroll")                                                        \
      for (int p = 0; p < 4; ++p) {                                            \
        int idx = p * 8192 + tid * 16;                                         \
        int n = idx >> 7, off = idx & 127;                                     \
        *(short8v*)(w2c[buf] + n * 144 + off) = w2r[p];                        \
      }                                                                        \
    }

  STAGE_W1(0, 0);
  LOAD_W2(0);
  WRITE_W2(0);
  __syncthreads();

  #pragma unroll 2
  for (int c = 0; c < 16; ++c) {
    const int buf = c & 1;
    if (c < 15) {
      STAGE_W1(buf ^ 1, c + 1);
      LOAD_W2(c + 1);
    }

    // GEMM1 (swapped): h1^T[f-tile][xrow] = W1chunk @ x^T, k = 256, 4 f-tiles
    float4v g1[2][4] = {};  // [ct][ft]
    #pragma unroll
    for (int kc = 0; kc < 8; ++kc) {
      #pragma unroll
      for (int ft = 0; ft < 4; ++ft) {
        int r = ft * 16 + ln15;
        short8v a = *(const short8v*)(w1c[buf] + r * 512 +
                                      ((kc * 64 + gq * 16) ^ ((r & 7) << 4)));
        g1[0][ft] = mfma32(a, xr[0][kc], g1[0][ft]);
        g1[1][ft] = mfma32(a, xr[1][kc], g1[1][ft]);
      }
    }
    // bias + relu + pack into two mfma32 A-frags per ct:
    // pa8[ct][half][e=4*(ft&1)+j] holds f-local = half*32 + 16*(ft&1) + 4gq + j
    // == k-perm'd W2 position p = half*32 + 8gq + e
    short8v pa8[2][2];
    #pragma unroll
    for (int ft = 0; ft < 4; ++ft) {
      float4v bv4 = *(const float4v*)(b1s + c * 64 + ft * 16 + 4 * gq);
      #pragma unroll
      for (int ct = 0; ct < 2; ++ct)
        #pragma unroll
        for (int j = 0; j < 4; ++j) {
          float v = g1[ct][ft][j] + bv4[j];
          v = v > 0.f ? v : 0.f;
          pa8[ct][ft >> 1][(ft & 1) * 4 + j] = (short)f2bf(v);
        }
    }
    // GEMM2: ff += h1 @ W2chunk (two mfma32 per nt per ct; K=64 = whole chunk)
    #pragma unroll
    for (int nt = 0; nt < 16; ++nt) {
      const char* base = w2c[buf] + (nt * 16 + ln15) * 144 + gq * 16;
      short8v wb0 = *(const short8v*)(base);
      short8v wb1 = *(const short8v*)(base + 64);
      ff[0][nt] = mfma32(pa8[0][0], wb0, ff[0][nt]);
      ff[0][nt] = mfma32(pa8[0][1], wb1, ff[0][nt]);
      ff[1][nt] = mfma32(pa8[1][0], wb0, ff[1][nt]);
      ff[1][nt] = mfma32(pa8[1][1], wb1, ff[1][nt]);
    }

    if (c < 15) WRITE_W2(buf ^ 1);
    __syncthreads();
  }

  // ---- epilogue: + b2 + x residual, LN2 per row (16-lane reduce), f32 out ----
  #pragma unroll
  for (int ct = 0; ct < 2; ++ct)
    #pragma unroll
    for (int j = 0; j < 4; ++j) {
      int r2 = wrow0 + ct * 16 + 4 * gq + j;
      float sum = 0.f, sq = 0.f;
      float vv[16];
      #pragma unroll
      for (int nt = 0; nt < 16; ++nt) {
        int col = nt * 16 + ln15;
        float xv = bf2f(X[(size_t)r2 * 256 + col]);
        float v = ff[ct][nt][j] + b2[col] + xv;
        vv[nt] = v;
        sum += v;
        sq += v * v;
      }
      #pragma unroll
      for (int m = 1; m <= 8; m <<= 1) {
        sum += __shfl_xor(sum, m);
        sq += __shfl_xor(sq, m);
      }
      float mu = sum * (1.f / 256.f);
      float var = sq * (1.f / 256.f) - mu * mu;
      float rstd = rsqrtf(var + 1e-5f);
      #pragma unroll
      for (int nt = 0; nt < 16; ++nt) {
        int col = nt * 16 + ln15;
        out[(size_t)r2 * 256 + col] = (vv[nt] - mu) * rstd * g2[col] + be2[col];
      }
    }
  #undef STAGE_W1
  #undef LOAD_W2
  #undef WRITE_W2
}

extern "C" void kernel_launch(void* const* d_in, const int* in_sizes, int n_in,
                              void* d_out, int out_size, void* d_ws, size_t ws_size,
                              hipStream_t stream) {
  (void)in_sizes; (void)n_in; (void)out_size;
  const float* query = (const float*)d_in[0];
  const float* kv    = (const float*)d_in[1];
  const float* Wqm = (const float*)d_in[2];  const float* bq = (const float*)d_in[3];
  const float* Wkm = (const float*)d_in[4];  const float* bk = (const float*)d_in[5];
  const float* Wvm = (const float*)d_in[6];  const float* bv = (const float*)d_in[7];
  const float* Wom = (const float*)d_in[8];  const float* bo = (const float*)d_in[9];
  const float* ln1g = (const float*)d_in[10]; const float* ln1b = (const float*)d_in[11];
  const float* W1m = (const float*)d_in[12]; const float* b1 = (const float*)d_in[13];
  const float* W2m = (const float*)d_in[14]; const float* b2 = (const float*)d_in[15];
  const float* ln2g = (const float*)d_in[16]; const float* ln2b = (const float*)d_in[17];
  float* out = (float*)d_out;

  char* ws = (char*)d_ws;
  const size_t MB = 1ull << 20;
  if (ws_size < 130 * MB) return;

  // workspace layout (all bf16); Q/K/V/ctx are head-major [8][65536][32]
  u16* Vw   = (u16*)(ws);            // [0,32M)
  u16* ctxw = (u16*)(ws + 32 * MB);  // [32,64M)
  u16* Qw   = (u16*)(ws + 64 * MB);  // dead after attn
  u16* xw   = (u16*)(ws + 64 * MB);  // aliases Qw
  u16* Kw   = (u16*)(ws + 96 * MB);
  char* wb = ws + 128 * MB;
  u16* Wqt = (u16*)(wb);
  u16* Wkt = (u16*)(wb + 131072);
  u16* Wvt = (u16*)(wb + 262144);
  u16* Wot = (u16*)(wb + 393216);
  u16* W1t = (u16*)(wb + 524288);
  u16* W2t = (u16*)(wb + 1048576);

  cvt_wT<<<dim3(64, 6), 256, 0, stream>>>(Wqm, Wkm, Wvm, Wom, W1m, W2m,
                                          Wqt, Wkt, Wvt, Wot, W1t, W2t);
  gemm_q<<<dim3(512, 2), 256, 0, stream>>>(query, Wqt, bq, Qw);
  gemm_kv<<<dim3(512, 4), 256, 0, stream>>>(kv, Wkt, bk, bv, Kw, Vw);
  attn_v2<<<dim3(2048), 256, 0, stream>>>(Qw, Kw, Vw, ctxw);
  gemm_wo_ln<<<dim3(512), 256, 0, stream>>>(ctxw, Wot, bo, query, ln1g, ln1b, xw);
  ffn_v9<<<dim3(256), 512, 0, stream>>>(xw, W1t, W2t, b1, b2, ln2g, ln2b, out);
}

// Round 14
// 292.940 us; speedup vs baseline: 1.1365x; 1.1365x over previous
//
#include <hip/hip_runtime.h>

#define DEV __device__ __forceinline__

typedef short short4v __attribute__((ext_vector_type(4)));
typedef short short8v __attribute__((ext_vector_type(8)));
typedef float float4v __attribute__((ext_vector_type(4)));
typedef unsigned short u16;

#define S32E ((size_t)65536 * 32)   // head stride, elements (u16)
#define S64B ((size_t)65536 * 64)   // head stride, bytes

DEV unsigned short f2bf(float f) {
  unsigned u = __builtin_bit_cast(unsigned, f);
  u += 0x7fffu + ((u >> 16) & 1u);
  return (unsigned short)(u >> 16);
}
DEV float bf2f(unsigned short h) {
  unsigned u = ((unsigned)h) << 16;
  return __builtin_bit_cast(float, u);
}
DEV float4v mfma32(short8v a, short8v b, float4v c) {
  return __builtin_amdgcn_mfma_f32_16x16x32_bf16(a, b, c, 0, 0, 0);
}
DEV void async16(const void* g, void* l) {
  __builtin_amdgcn_global_load_lds(
      (const __attribute__((address_space(1))) unsigned*)g,
      (__attribute__((address_space(3))) unsigned*)l, 16, 0, 0);
}
DEV short8v cvt8(float4v a, float4v b) {
  short8v o;
  o[0] = (short)f2bf(a[0]); o[1] = (short)f2bf(a[1]);
  o[2] = (short)f2bf(a[2]); o[3] = (short)f2bf(a[3]);
  o[4] = (short)f2bf(b[0]); o[5] = (short)f2bf(b[1]);
  o[6] = (short)f2bf(b[2]); o[7] = (short)f2bf(b[3]);
  return o;
}

// ------------- weight convert + transpose (LDS-tiled, coalesced) -------------
__global__ __launch_bounds__(256)
void cvt_wT(const float* Wq, const float* Wk, const float* Wv, const float* Wo,
            const float* W1, const float* W2,
            u16* Wqt, u16* Wkt, u16* Wvt, u16* Wot, u16* W1t, u16* W2t) {
  __shared__ float ld[64 * 69];
  const float* src; u16* dst; int R, C; bool permk = false;
  switch (blockIdx.y) {
    case 0: src = Wq; dst = Wqt; R = 256;  C = 256;  break;
    case 1: src = Wk; dst = Wkt; R = 256;  C = 256;  break;
    case 2: src = Wv; dst = Wvt; R = 256;  C = 256;  break;
    case 3: src = Wo; dst = Wot; R = 256;  C = 256;  break;
    case 4: src = W1; dst = W1t; R = 256;  C = 1024; break;
    default: src = W2; dst = W2t; R = 1024; C = 256; permk = true; break;
  }
  const int ntile = (R >> 6) * (C >> 6);
  if ((int)blockIdx.x >= ntile) return;
  const int tf = blockIdx.x % (R >> 6);
  const int tn = blockIdx.x / (R >> 6);
  const int r0 = tf << 6, c0 = tn << 6;
  const int tid = threadIdx.x;
  {
    int lr = tid >> 4, lc = (tid & 15) << 2;
    #pragma unroll
    for (int ps = 0; ps < 4; ++ps) {
      int r = ps * 16 + lr;
      float4v v = *(const float4v*)(src + (size_t)(r0 + r) * C + c0 + lc);
      #pragma unroll
      for (int e = 0; e < 4; ++e) ld[r * 69 + lc + e] = v[e];
    }
  }
  __syncthreads();
  {
    int p8 = (tid & 7) << 3;
    #pragma unroll
    for (int ps = 0; ps < 2; ++ps) {
      int n = ps * 32 + (tid >> 3);
      short8v o;
      #pragma unroll
      for (int e = 0; e < 8; ++e) {
        int p = p8 + e;
        int fl = p;
        if (permk) {
          int m = p & 31;
          fl = (p & 32) + 16 * ((m >> 2) & 1) + 4 * (m >> 3) + (m & 3);
        }
        o[e] = (short)f2bf(ld[fl * 69 + n]);
      }
      *(short8v*)(dst + (size_t)(c0 + n) * R + r0 + p8) = o;
    }
  }
}

// ---------------- Q projection GEMM: out = A_f32 @ Wt^T + bias, head-major out ----
__global__ __launch_bounds__(256, 2)
void gemm_q(const float* __restrict__ A, const u16* __restrict__ Wt,
            const float* __restrict__ bias, u16* __restrict__ out) {
  __shared__ alignas(16) char sm[32768];
  char* sa = sm;
  char* sb = sm + 16384;
  const int tid = threadIdx.x;
  const int w = tid >> 6, lane = tid & 63;
  const int ln15 = lane & 15, gq = lane >> 4;
  const int wr = w >> 1, wc = w & 1;
  const int m0 = blockIdx.x * 128, n0 = blockIdx.y * 128;
  const char* Wb = (const char*)Wt;

  float4v acc[4][4] = {};
  for (int kk = 0; kk < 4; ++kk) {
    #pragma unroll
    for (int p = 0; p < 4; ++p) {
      int L = p * 4096 + w * 1024 + lane * 16;
      int row = L >> 7, colb = L & 127;
      const float* src = A + (size_t)(m0 + row) * 256 + kk * 64 + (colb >> 1);
      float4v f0 = *(const float4v*)(src);
      float4v f1 = *(const float4v*)(src + 4);
      *(short8v*)(sa + row * 128 + (colb ^ ((row & 7) << 4))) = cvt8(f0, f1);
    }
    #pragma unroll
    for (int p = 0; p < 4; ++p) {
      int L = p * 4096 + w * 1024 + lane * 16;
      int row = L >> 7, colb = L & 127;
      int sw = colb ^ ((row & 7) << 4);
      async16(Wb + (size_t)(n0 + row) * 512 + kk * 128 + sw, sb + p * 4096 + w * 1024);
    }
    __syncthreads();
    #pragma unroll
    for (int ks = 0; ks < 2; ++ks) {
      short8v af[4], bfr[4];
      #pragma unroll
      for (int mf = 0; mf < 4; ++mf) {
        int r = wr * 64 + mf * 16 + ln15;
        af[mf] = *(const short8v*)(sa + r * 128 + ((ks * 64 + gq * 16) ^ ((r & 7) << 4)));
      }
      #pragma unroll
      for (int nf = 0; nf < 4; ++nf) {
        int r = wc * 64 + nf * 16 + ln15;
        bfr[nf] = *(const short8v*)(sb + r * 128 + ((ks * 64 + gq * 16) ^ ((r & 7) << 4)));
      }
      #pragma unroll
      for (int mf = 0; mf < 4; ++mf)
        #pragma unroll
        for (int nf = 0; nf < 4; ++nf)
          acc[mf][nf] = mfma32(af[mf], bfr[nf], acc[mf][nf]);
    }
    __syncthreads();
  }
  #pragma unroll
  for (int nf = 0; nf < 4; ++nf) {
    int col = n0 + wc * 64 + nf * 16 + ln15;
    float bb = bias[col];
    #pragma unroll
    for (int mf = 0; mf < 4; ++mf) {
      int rb = m0 + wr * 64 + mf * 16 + 4 * gq;
      #pragma unroll
      for (int j = 0; j < 4; ++j) {
        float v = acc[mf][nf][j] + bb;
        out[(size_t)(col >> 5) * S32E + (size_t)(rb + j) * 32 + (col & 31)] = f2bf(v);
      }
    }
  }
}

// ---------------- merged K/V projection GEMM (f32 A, head-major outputs) ----------------
__global__ __launch_bounds__(256, 2)
void gemm_kv(const float* __restrict__ A, const u16* __restrict__ Wt,
             const float* __restrict__ bk, const float* __restrict__ bv,
             u16* __restrict__ Kout, u16* __restrict__ Vout) {
  __shared__ alignas(16) char sm[32768];
  char* sa = sm;
  char* sb = sm + 16384;
  const int tid = threadIdx.x;
  const int w = tid >> 6, lane = tid & 63;
  const int ln15 = lane & 15, gq = lane >> 4;
  const int wr = w >> 1, wc = w & 1;
  const int m0 = blockIdx.x * 128, n0 = blockIdx.y * 128;
  const char* Wb = (const char*)Wt;

  float4v acc[4][4] = {};
  for (int kk = 0; kk < 4; ++kk) {
    #pragma unroll
    for (int p = 0; p < 4; ++p) {
      int L = p * 4096 + w * 1024 + lane * 16;
      int row = L >> 7, colb = L & 127;
      const float* src = A + (size_t)(m0 + row) * 256 + kk * 64 + (colb >> 1);
      float4v f0 = *(const float4v*)(src);
      float4v f1 = *(const float4v*)(src + 4);
      *(short8v*)(sa + row * 128 + (colb ^ ((row & 7) << 4))) = cvt8(f0, f1);
    }
    #pragma unroll
    for (int p = 0; p < 4; ++p) {
      int L = p * 4096 + w * 1024 + lane * 16;
      int row = L >> 7, colb = L & 127;
      int sw = colb ^ ((row & 7) << 4);
      async16(Wb + (size_t)(n0 + row) * 512 + kk * 128 + sw, sb + p * 4096 + w * 1024);
    }
    __syncthreads();
    #pragma unroll
    for (int ks = 0; ks < 2; ++ks) {
      short8v af[4], bfr[4];
      #pragma unroll
      for (int mf = 0; mf < 4; ++mf) {
        int r = wr * 64 + mf * 16 + ln15;
        af[mf] = *(const short8v*)(sa + r * 128 + ((ks * 64 + gq * 16) ^ ((r & 7) << 4)));
      }
      #pragma unroll
      for (int nf = 0; nf < 4; ++nf) {
        int r = wc * 64 + nf * 16 + ln15;
        bfr[nf] = *(const short8v*)(sb + r * 128 + ((ks * 64 + gq * 16) ^ ((r & 7) << 4)));
      }
      #pragma unroll
      for (int mf = 0; mf < 4; ++mf)
        #pragma unroll
        for (int nf = 0; nf < 4; ++nf)
          acc[mf][nf] = mfma32(af[mf], bfr[nf], acc[mf][nf]);
    }
    __syncthreads();
  }
  #pragma unroll
  for (int nf = 0; nf < 4; ++nf) {
    int col = n0 + wc * 64 + nf * 16 + ln15;  // 0..511
    const bool isK = col < 256;
    const int c2 = col & 255;
    u16* outp = isK ? Kout : Vout;
    float bb = isK ? bk[c2] : bv[c2];
    const size_t hb = (size_t)(c2 >> 5) * S32E;
    const int d = c2 & 31;
    #pragma unroll
    for (int mf = 0; mf < 4; ++mf) {
      int rb = m0 + wr * 64 + mf * 16 + 4 * gq;
      #pragma unroll
      for (int j = 0; j < 4; ++j)
        outp[hb + (size_t)(rb + j) * 32 + d] = f2bf(acc[mf][nf][j] + bb);
    }
  }
}

// ---- Wo GEMM + residual + LN1 fused: x = LN1(q_in + ctx@Wo + bo), bf16 out ----
__global__ __launch_bounds__(256, 2)
void gemm_wo_ln(const u16* __restrict__ A, const u16* __restrict__ Wt,
                const float* __restrict__ bias, const float* __restrict__ resid,
                const float* __restrict__ lng, const float* __restrict__ lnb,
                u16* __restrict__ xout) {
  __shared__ alignas(16) char sa[16384];   // A tile [128][128B], XOR-swizzled
  __shared__ alignas(16) char sb[32768];   // B tile [256][128B], XOR-swizzled
  __shared__ float red[512];               // [128 rows][2 wc][2 {sum,sq}]
  const int tid = threadIdx.x;
  const int w = tid >> 6, lane = tid & 63;
  const int ln15 = lane & 15, gq = lane >> 4;
  const int wr = w >> 1, wc = w & 1;
  const int m0 = blockIdx.x * 128;
  const char* Ab = (const char*)A;
  const char* Wb = (const char*)Wt;

  float4v acc[4][8] = {};
  for (int kk = 0; kk < 4; ++kk) {
    #pragma unroll
    for (int p = 0; p < 4; ++p) {
      int L = p * 4096 + tid * 16;
      int row = L >> 7, colb = L & 127;
      int sw = colb ^ ((row & 7) << 4);
      int b = kk * 128 + sw;
      async16(Ab + (size_t)(b >> 6) * S64B + (size_t)(m0 + row) * 64 + (b & 63),
              sa + L);
    }
    #pragma unroll
    for (int p = 0; p < 8; ++p) {
      int L = p * 4096 + tid * 16;
      int row = L >> 7, colb = L & 127;
      int sw = colb ^ ((row & 7) << 4);
      async16(Wb + (size_t)row * 512 + kk * 128 + sw, sb + L);
    }
    __syncthreads();
    #pragma unroll
    for (int ks = 0; ks < 2; ++ks) {
      short8v af[4], bfr[8];
      #pragma unroll
      for (int mf = 0; mf < 4; ++mf) {
        int r = wr * 64 + mf * 16 + ln15;
        af[mf] = *(const short8v*)(sa + r * 128 + ((ks * 64 + gq * 16) ^ ((r & 7) << 4)));
      }
      #pragma unroll
      for (int nf = 0; nf < 8; ++nf) {
        int r = wc * 128 + nf * 16 + ln15;
        bfr[nf] = *(const short8v*)(sb + r * 128 + ((ks * 64 + gq * 16) ^ ((r & 7) << 4)));
      }
      #pragma unroll
      for (int mf = 0; mf < 4; ++mf)
        #pragma unroll
        for (int nf = 0; nf < 8; ++nf)
          acc[mf][nf] = mfma32(af[mf], bfr[nf], acc[mf][nf]);
    }
    __syncthreads();
  }

  #pragma unroll
  for (int mf = 0; mf < 4; ++mf)
    #pragma unroll
    for (int j = 0; j < 4; ++j) {
      int lr = wr * 64 + mf * 16 + 4 * gq + j;   // local row 0..127
      int r2 = m0 + lr;
      float sum = 0.f, sq = 0.f;
      #pragma unroll
      for (int nf = 0; nf < 8; ++nf) {
        int col = wc * 128 + nf * 16 + ln15;
        float v = acc[mf][nf][j] + bias[col] + resid[(size_t)r2 * 256 + col];
        acc[mf][nf][j] = v;
        sum += v;
        sq += v * v;
      }
      #pragma unroll
      for (int m = 1; m <= 8; m <<= 1) {
        sum += __shfl_xor(sum, m);
        sq += __shfl_xor(sq, m);
      }
      if (ln15 == 0) {
        red[lr * 4 + wc * 2] = sum;
        red[lr * 4 + wc * 2 + 1] = sq;
      }
    }
  __syncthreads();

  #pragma unroll
  for (int mf = 0; mf < 4; ++mf)
    #pragma unroll
    for (int j = 0; j < 4; ++j) {
      int lr = wr * 64 + mf * 16 + 4 * gq + j;
      int r2 = m0 + lr;
      float S = red[lr * 4] + red[lr * 4 + 2];
      float S2 = red[lr * 4 + 1] + red[lr * 4 + 3];
      float mu = S * (1.f / 256.f);
      float var = S2 * (1.f / 256.f) - mu * mu;
      float rstd = rsqrtf(var + 1e-5f);
      #pragma unroll
      for (int nf = 0; nf < 8; ++nf) {
        int col = wc * 128 + nf * 16 + ln15;
        float o = (acc[mf][nf][j] - mu) * rstd * lng[col] + lnb[col];
        xout[(size_t)r2 * 256 + col] = f2bf(o);
      }
    }
}

// ---------------- windowed attention v3: one block per (window, head) ----------------
// K staged [256][80B] (proven); V staged d-major [32 d][528B] with keys placed
// at sigma^{-1}(k) per 32-block so PV runs as mfma32 with b128 A-frag reads.
__global__ __launch_bounds__(256, 2)
void attn_v3(const u16* __restrict__ Qg, const u16* __restrict__ Kg,
             const u16* __restrict__ Vg, u16* __restrict__ ctx) {
  __shared__ alignas(16) char ks[256 * 80];
  __shared__ alignas(16) char vsd[32 * 528];
  const int bw = blockIdx.x;
  const int win = bw >> 3, head = bw & 7;
  const int tid = threadIdx.x;
  const int w = tid >> 6, lane = tid & 63;
  const int ln15 = lane & 15, gq = lane >> 4;
  const int tok0 = win << 8;
  const u16* Qh = Qg + head * S32E + (size_t)tok0 * 32;
  const u16* Kh = Kg + head * S32E + (size_t)tok0 * 32;
  const u16* Vh = Vg + head * S32E + (size_t)tok0 * 32;
  u16* Ch = ctx + head * S32E + (size_t)tok0 * 32;

  // stage K [256][32] -> [256][80B]; V -> d-major [32][264 u16] with key perm
  #pragma unroll
  for (int i = 0; i < 4; ++i) {
    int L = i * 4096 + tid * 16;
    int row = L >> 6, colb = L & 63;
    short8v kv0 = *(const short8v*)((const char*)Kh + L);
    *(short8v*)(ks + row * 80 + colb) = kv0;
    short8v vv0 = *(const short8v*)((const char*)Vh + L);
    int kl = row & 31;
    int p = 8 * ((kl >> 2) & 3) + 4 * (kl >> 4) + (kl & 3);
    int pos = (row >> 5) * 32 + p;           // key position in LDS
    int dbase = colb >> 1;
    #pragma unroll
    for (int e = 0; e < 8; ++e)
      *(u16*)(vsd + (dbase + e) * 528 + pos * 2) = (u16)vv0[e];
  }
  __syncthreads();

  const float KSC = (float)(1.4426950408889634 / 5.656854249492381);  // log2e/sqrt(32)

  for (int pass = 0; pass < 2; ++pass) {
    const int q0 = w * 64 + pass * 32;

    short8v qf[2];
    #pragma unroll
    for (int qi = 0; qi < 2; ++qi)
      qf[qi] = *(const short8v*)(Qh + (size_t)(q0 + qi * 16 + ln15) * 32 + gq * 8);

    // S^T = K @ Q^T: s[kf][qi] lane holds P[q=ln15][key = 16kf + 4gq + j]
    float4v s[16][2];
    #pragma unroll
    for (int kf = 0; kf < 16; ++kf) {
      short8v kfr = *(const short8v*)(ks + (16 * kf + ln15) * 80 + gq * 16);
      float4v z = {0.f, 0.f, 0.f, 0.f};
      s[kf][0] = mfma32(kfr, qf[0], z);
      s[kf][1] = mfma32(kfr, qf[1], z);
    }

    float rs[2];
    #pragma unroll
    for (int qi = 0; qi < 2; ++qi) {
      float mx = -1e30f;
      #pragma unroll
      for (int kf = 0; kf < 16; ++kf)
        #pragma unroll
        for (int j = 0; j < 4; ++j) mx = fmaxf(mx, s[kf][qi][j]);
      mx = fmaxf(mx, __shfl_xor(mx, 16));
      mx = fmaxf(mx, __shfl_xor(mx, 32));
      float mk = mx * KSC;
      float sum = 0.f;
      #pragma unroll
      for (int kf = 0; kf < 16; ++kf)
        #pragma unroll
        for (int j = 0; j < 4; ++j) {
          float p = exp2f(fmaf(s[kf][qi][j], KSC, -mk));
          s[kf][qi][j] = p;
          sum += p;
        }
      sum += __shfl_xor(sum, 16);
      sum += __shfl_xor(sum, 32);
      rs[qi] = 1.0f / sum;
    }

    // ctx^T = V^T @ P^T via mfma32: pb8 slot e=4kf'+j holds key 32ks+16kf'+4gq+j;
    // vsd position p holds key sigma(p) -> operands agree per contract position.
    float4v cacc[2][2] = {};  // [df][qi]
    #pragma unroll
    for (int ksI = 0; ksI < 8; ++ksI) {
      short8v pb[2];
      pb[0] = cvt8(s[2 * ksI][0], s[2 * ksI + 1][0]);
      pb[1] = cvt8(s[2 * ksI][1], s[2 * ksI + 1][1]);
      #pragma unroll
      for (int df = 0; df < 2; ++df) {
        short8v va = *(const short8v*)(vsd + (size_t)(df * 16 + ln15) * 528 +
                                       ksI * 64 + gq * 16);
        cacc[df][0] = mfma32(va, pb[0], cacc[df][0]);
        cacc[df][1] = mfma32(va, pb[1], cacc[df][1]);
      }
    }

    #pragma unroll
    for (int qi = 0; qi < 2; ++qi)
      #pragma unroll
      for (int df = 0; df < 2; ++df) {
        short4v o;
        #pragma unroll
        for (int j = 0; j < 4; ++j) o[j] = (short)f2bf(cacc[df][qi][j] * rs[qi]);
        *(short4v*)(Ch + (size_t)(q0 + qi * 16 + ln15) * 32 + df * 16 + 4 * gq) = o;
      }
  }
}

// ---------------- fused FFN v6 + residual + LN2 (R12-proven, verbatim) ----------------
__global__ __launch_bounds__(512, 2)
void ffn_v6(const u16* __restrict__ X, const u16* __restrict__ W1t,
            const u16* __restrict__ W2tp, const float* __restrict__ b1,
            const float* __restrict__ b2, const float* __restrict__ g2,
            const float* __restrict__ be2, float* __restrict__ out) {
  __shared__ alignas(16) char w1c[2][16384];   // [32 f][512B k], XOR-swizzled
  __shared__ alignas(16) char w2c[2][20480];   // [256 n][80B] (64B data + 16 pad)
  __shared__ alignas(16) float b1s[1024];
  const int tid = threadIdx.x;  // 0..511
  const int w = tid >> 6, lane = tid & 63;
  const int ln15 = lane & 15, gq = lane >> 4;
  const int m0 = blockIdx.x * 256;
  const int wrow0 = m0 + w * 32;

  b1s[tid] = b1[tid];
  b1s[tid + 512] = b1[tid + 512];

  short8v xr[2][8];
  #pragma unroll
  for (int ct = 0; ct < 2; ++ct)
    #pragma unroll
    for (int kc = 0; kc < 8; ++kc)
      xr[ct][kc] = *(const short8v*)(X + (size_t)(wrow0 + ct * 16 + ln15) * 256 + kc * 32 + gq * 8);

  float4v ff[2][16] = {};
  short8v w2r[2];

  const char* W1b = (const char*)W1t;
  const char* W2b = (const char*)W2tp;

  #define STAGE_W1(buf, c)                                                     \
    {                                                                          \
      _Pragma("unroll")                                                        \
      for (int p = 0; p < 2; ++p) {                                            \
        int L = p * 8192 + tid * 16;                                           \
        int r = L >> 9, colb = L & 511;                                        \
        async16(W1b + (size_t)((c) * 32 + r) * 512 + (colb ^ ((r & 7) << 4)),  \
                w1c[buf] + L);                                                 \
      }                                                                        \
    }
  #define LOAD_W2(c)                                                           \
    {                                                                          \
      _Pragma("unroll")                                                        \
      for (int p = 0; p < 2; ++p) {                                            \
        int idx = p * 8192 + tid * 16;                                         \
        int n = idx >> 6, off = idx & 63;                                      \
        w2r[p] = *(const short8v*)(W2b + (size_t)n * 2048 + (c) * 64 + off);   \
      }                                                                        \
    }
  #define WRITE_W2(buf)                                                        \
    {                                                                          \
      _Pragma("unroll")                                                        \
      for (int p = 0; p < 2; ++p) {                                            \
        int idx = p * 8192 + tid * 16;                                         \
        int n = idx >> 6, off = idx & 63;                                      \
        *(short8v*)(w2c[buf] + n * 80 + off) = w2r[p];                         \
      }                                                                        \
    }

  STAGE_W1(0, 0);
  LOAD_W2(0);
  WRITE_W2(0);
  __syncthreads();

  #pragma unroll 2
  for (int c = 0; c < 32; ++c) {
    const int buf = c & 1;
    if (c < 31) {
      STAGE_W1(buf ^ 1, c + 1);
      LOAD_W2(c + 1);
    }

    float4v g1[2][2] = {};
    #pragma unroll
    for (int kc = 0; kc < 8; ++kc) {
      #pragma unroll
      for (int ft = 0; ft < 2; ++ft) {
        int r = ft * 16 + ln15;
        short8v a = *(const short8v*)(w1c[buf] + r * 512 +
                                      ((kc * 64 + gq * 16) ^ ((r & 7) << 4)));
        g1[0][ft] = mfma32(a, xr[0][kc], g1[0][ft]);
        g1[1][ft] = mfma32(a, xr[1][kc], g1[1][ft]);
      }
    }
    short8v pa8[2];
    #pragma unroll
    for (int ft = 0; ft < 2; ++ft) {
      float4v bv4 = *(const float4v*)(b1s + c * 32 + ft * 16 + 4 * gq);
      #pragma unroll
      for (int ct = 0; ct < 2; ++ct)
        #pragma unroll
        for (int j = 0; j < 4; ++j) {
          float v = g1[ct][ft][j] + bv4[j];
          v = v > 0.f ? v : 0.f;
          pa8[ct][ft * 4 + j] = (short)f2bf(v);
        }
    }
    #pragma unroll
    for (int nt = 0; nt < 16; ++nt) {
      short8v wb = *(const short8v*)(w2c[buf] + (nt * 16 + ln15) * 80 + gq * 16);
      ff[0][nt] = mfma32(pa8[0], wb, ff[0][nt]);
      ff[1][nt] = mfma32(pa8[1], wb, ff[1][nt]);
    }

    if (c < 31) WRITE_W2(buf ^ 1);
    __syncthreads();
  }

  #pragma unroll
  for (int ct = 0; ct < 2; ++ct)
    #pragma unroll
    for (int j = 0; j < 4; ++j) {
      int r2 = wrow0 + ct * 16 + 4 * gq + j;
      float sum = 0.f, sq = 0.f;
      float vv[16];
      #pragma unroll
      for (int nt = 0; nt < 16; ++nt) {
        int col = nt * 16 + ln15;
        float xv = bf2f(X[(size_t)r2 * 256 + col]);
        float v = ff[ct][nt][j] + b2[col] + xv;
        vv[nt] = v;
        sum += v;
        sq += v * v;
      }
      #pragma unroll
      for (int m = 1; m <= 8; m <<= 1) {
        sum += __shfl_xor(sum, m);
        sq += __shfl_xor(sq, m);
      }
      float mu = sum * (1.f / 256.f);
      float var = sq * (1.f / 256.f) - mu * mu;
      float rstd = rsqrtf(var + 1e-5f);
      #pragma unroll
      for (int nt = 0; nt < 16; ++nt) {
        int col = nt * 16 + ln15;
        out[(size_t)r2 * 256 + col] = (vv[nt] - mu) * rstd * g2[col] + be2[col];
      }
    }
  #undef STAGE_W1
  #undef LOAD_W2
  #undef WRITE_W2
}

extern "C" void kernel_launch(void* const* d_in, const int* in_sizes, int n_in,
                              void* d_out, int out_size, void* d_ws, size_t ws_size,
                              hipStream_t stream) {
  (void)in_sizes; (void)n_in; (void)out_size;
  const float* query = (const float*)d_in[0];
  const float* kv    = (const float*)d_in[1];
  const float* Wqm = (const float*)d_in[2];  const float* bq = (const float*)d_in[3];
  const float* Wkm = (const float*)d_in[4];  const float* bk = (const float*)d_in[5];
  const float* Wvm = (const float*)d_in[6];  const float* bv = (const float*)d_in[7];
  const float* Wom = (const float*)d_in[8];  const float* bo = (const float*)d_in[9];
  const float* ln1g = (const float*)d_in[10]; const float* ln1b = (const float*)d_in[11];
  const float* W1m = (const float*)d_in[12]; const float* b1 = (const float*)d_in[13];
  const float* W2m = (const float*)d_in[14]; const float* b2 = (const float*)d_in[15];
  const float* ln2g = (const float*)d_in[16]; const float* ln2b = (const float*)d_in[17];
  float* out = (float*)d_out;

  char* ws = (char*)d_ws;
  const size_t MB = 1ull << 20;
  if (ws_size < 130 * MB) return;

  // workspace layout (all bf16); Q/K/V/ctx are head-major [8][65536][32]
  u16* Vw   = (u16*)(ws);            // [0,32M)
  u16* ctxw = (u16*)(ws + 32 * MB);  // [32,64M)
  u16* Qw   = (u16*)(ws + 64 * MB);  // dead after attn
  u16* xw   = (u16*)(ws + 64 * MB);  // aliases Qw
  u16* Kw   = (u16*)(ws + 96 * MB);
  char* wb = ws + 128 * MB;
  u16* Wqt = (u16*)(wb);
  u16* Wkt = (u16*)(wb + 131072);
  u16* Wvt = (u16*)(wb + 262144);
  u16* Wot = (u16*)(wb + 393216);
  u16* W1t = (u16*)(wb + 524288);
  u16* W2t = (u16*)(wb + 1048576);

  cvt_wT<<<dim3(64, 6), 256, 0, stream>>>(Wqm, Wkm, Wvm, Wom, W1m, W2m,
                                          Wqt, Wkt, Wvt, Wot, W1t, W2t);
  gemm_q<<<dim3(512, 2), 256, 0, stream>>>(query, Wqt, bq, Qw);
  gemm_kv<<<dim3(512, 4), 256, 0, stream>>>(kv, Wkt, bk, bv, Kw, Vw);
  attn_v3<<<dim3(2048), 256, 0, stream>>>(Qw, Kw, Vw, ctxw);
  gemm_wo_ln<<<dim3(512), 256, 0, stream>>>(ctxw, Wot, bo, query, ln1g, ln1b, xw);
  ffn_v6<<<dim3(256), 512, 0, stream>>>(xw, W1t, W2t, b1, b2, ln2g, ln2b, out);
}

// Round 15
// 288.225 us; speedup vs baseline: 1.1551x; 1.0164x over previous
//
#include <hip/hip_runtime.h>

#define DEV __device__ __forceinline__

typedef short short4v __attribute__((ext_vector_type(4)));
typedef short short8v __attribute__((ext_vector_type(8)));
typedef float float4v __attribute__((ext_vector_type(4)));
typedef unsigned short u16;

#define S32E ((size_t)65536 * 32)   // head stride, elements (u16)
#define S64B ((size_t)65536 * 64)   // head stride, bytes

DEV unsigned short f2bf(float f) {
  unsigned u = __builtin_bit_cast(unsigned, f);
  u += 0x7fffu + ((u >> 16) & 1u);
  return (unsigned short)(u >> 16);
}
DEV float bf2f(unsigned short h) {
  unsigned u = ((unsigned)h) << 16;
  return __builtin_bit_cast(float, u);
}
DEV float4v mfma32(short8v a, short8v b, float4v c) {
  return __builtin_amdgcn_mfma_f32_16x16x32_bf16(a, b, c, 0, 0, 0);
}
DEV float4v mfma16(short4v a, short4v b, float4v c) {
  return __builtin_amdgcn_mfma_f32_16x16x16bf16_1k(a, b, c, 0, 0, 0);
}
DEV void async16(const void* g, void* l) {
  __builtin_amdgcn_global_load_lds(
      (const __attribute__((address_space(1))) unsigned*)g,
      (__attribute__((address_space(3))) unsigned*)l, 16, 0, 0);
}
DEV short4v cvt4(float4v v) {
  short4v r;
  r[0] = (short)f2bf(v[0]); r[1] = (short)f2bf(v[1]);
  r[2] = (short)f2bf(v[2]); r[3] = (short)f2bf(v[3]);
  return r;
}
DEV short8v cvt8(float4v a, float4v b) {
  short8v o;
  o[0] = (short)f2bf(a[0]); o[1] = (short)f2bf(a[1]);
  o[2] = (short)f2bf(a[2]); o[3] = (short)f2bf(a[3]);
  o[4] = (short)f2bf(b[0]); o[5] = (short)f2bf(b[1]);
  o[6] = (short)f2bf(b[2]); o[7] = (short)f2bf(b[3]);
  return o;
}

// ------------- weight convert + transpose (LDS-tiled, coalesced) -------------
__global__ __launch_bounds__(256)
void cvt_wT(const float* Wq, const float* Wk, const float* Wv, const float* Wo,
            const float* W1, const float* W2,
            u16* Wqt, u16* Wkt, u16* Wvt, u16* Wot, u16* W1t, u16* W2t) {
  __shared__ float ld[64 * 69];
  const float* src; u16* dst; int R, C; bool permk = false;
  switch (blockIdx.y) {
    case 0: src = Wq; dst = Wqt; R = 256;  C = 256;  break;
    case 1: src = Wk; dst = Wkt; R = 256;  C = 256;  break;
    case 2: src = Wv; dst = Wvt; R = 256;  C = 256;  break;
    case 3: src = Wo; dst = Wot; R = 256;  C = 256;  break;
    case 4: src = W1; dst = W1t; R = 256;  C = 1024; break;
    default: src = W2; dst = W2t; R = 1024; C = 256; permk = true; break;
  }
  const int ntile = (R >> 6) * (C >> 6);
  if ((int)blockIdx.x >= ntile) return;
  const int tf = blockIdx.x % (R >> 6);
  const int tn = blockIdx.x / (R >> 6);
  const int r0 = tf << 6, c0 = tn << 6;
  const int tid = threadIdx.x;
  {
    int lr = tid >> 4, lc = (tid & 15) << 2;
    #pragma unroll
    for (int ps = 0; ps < 4; ++ps) {
      int r = ps * 16 + lr;
      float4v v = *(const float4v*)(src + (size_t)(r0 + r) * C + c0 + lc);
      #pragma unroll
      for (int e = 0; e < 4; ++e) ld[r * 69 + lc + e] = v[e];
    }
  }
  __syncthreads();
  {
    int p8 = (tid & 7) << 3;
    #pragma unroll
    for (int ps = 0; ps < 2; ++ps) {
      int n = ps * 32 + (tid >> 3);
      short8v o;
      #pragma unroll
      for (int e = 0; e < 8; ++e) {
        int p = p8 + e;
        int fl = p;
        if (permk) {
          int m = p & 31;
          fl = (p & 32) + 16 * ((m >> 2) & 1) + 4 * (m >> 3) + (m & 3);
        }
        o[e] = (short)f2bf(ld[fl * 69 + n]);
      }
      *(short8v*)(dst + (size_t)(c0 + n) * R + r0 + p8) = o;
    }
  }
}

// ---------------- Q projection GEMM: out = A_f32 @ Wt^T + bias, head-major out ----
__global__ __launch_bounds__(256, 2)
void gemm_q(const float* __restrict__ A, const u16* __restrict__ Wt,
            const float* __restrict__ bias, u16* __restrict__ out) {
  __shared__ alignas(16) char sm[32768];
  char* sa = sm;
  char* sb = sm + 16384;
  const int tid = threadIdx.x;
  const int w = tid >> 6, lane = tid & 63;
  const int ln15 = lane & 15, gq = lane >> 4;
  const int wr = w >> 1, wc = w & 1;
  const int m0 = blockIdx.x * 128, n0 = blockIdx.y * 128;
  const char* Wb = (const char*)Wt;

  float4v acc[4][4] = {};
  for (int kk = 0; kk < 4; ++kk) {
    #pragma unroll
    for (int p = 0; p < 4; ++p) {
      int L = p * 4096 + w * 1024 + lane * 16;
      int row = L >> 7, colb = L & 127;
      const float* src = A + (size_t)(m0 + row) * 256 + kk * 64 + (colb >> 1);
      float4v f0 = *(const float4v*)(src);
      float4v f1 = *(const float4v*)(src + 4);
      *(short8v*)(sa + row * 128 + (colb ^ ((row & 7) << 4))) = cvt8(f0, f1);
    }
    #pragma unroll
    for (int p = 0; p < 4; ++p) {
      int L = p * 4096 + w * 1024 + lane * 16;
      int row = L >> 7, colb = L & 127;
      int sw = colb ^ ((row & 7) << 4);
      async16(Wb + (size_t)(n0 + row) * 512 + kk * 128 + sw, sb + p * 4096 + w * 1024);
    }
    __syncthreads();
    #pragma unroll
    for (int ks = 0; ks < 2; ++ks) {
      short8v af[4], bfr[4];
      #pragma unroll
      for (int mf = 0; mf < 4; ++mf) {
        int r = wr * 64 + mf * 16 + ln15;
        af[mf] = *(const short8v*)(sa + r * 128 + ((ks * 64 + gq * 16) ^ ((r & 7) << 4)));
      }
      #pragma unroll
      for (int nf = 0; nf < 4; ++nf) {
        int r = wc * 64 + nf * 16 + ln15;
        bfr[nf] = *(const short8v*)(sb + r * 128 + ((ks * 64 + gq * 16) ^ ((r & 7) << 4)));
      }
      #pragma unroll
      for (int mf = 0; mf < 4; ++mf)
        #pragma unroll
        for (int nf = 0; nf < 4; ++nf)
          acc[mf][nf] = mfma32(af[mf], bfr[nf], acc[mf][nf]);
    }
    __syncthreads();
  }
  #pragma unroll
  for (int nf = 0; nf < 4; ++nf) {
    int col = n0 + wc * 64 + nf * 16 + ln15;
    float bb = bias[col];
    #pragma unroll
    for (int mf = 0; mf < 4; ++mf) {
      int rb = m0 + wr * 64 + mf * 16 + 4 * gq;
      #pragma unroll
      for (int j = 0; j < 4; ++j) {
        float v = acc[mf][nf][j] + bb;
        out[(size_t)(col >> 5) * S32E + (size_t)(rb + j) * 32 + (col & 31)] = f2bf(v);
      }
    }
  }
}

// ---------------- merged K/V projection GEMM (f32 A, head-major outputs) ----------------
__global__ __launch_bounds__(256, 2)
void gemm_kv(const float* __restrict__ A, const u16* __restrict__ Wt,
             const float* __restrict__ bk, const float* __restrict__ bv,
             u16* __restrict__ Kout, u16* __restrict__ Vout) {
  __shared__ alignas(16) char sm[32768];
  char* sa = sm;
  char* sb = sm + 16384;
  const int tid = threadIdx.x;
  const int w = tid >> 6, lane = tid & 63;
  const int ln15 = lane & 15, gq = lane >> 4;
  const int wr = w >> 1, wc = w & 1;
  const int m0 = blockIdx.x * 128, n0 = blockIdx.y * 128;
  const char* Wb = (const char*)Wt;

  float4v acc[4][4] = {};
  for (int kk = 0; kk < 4; ++kk) {
    #pragma unroll
    for (int p = 0; p < 4; ++p) {
      int L = p * 4096 + w * 1024 + lane * 16;
      int row = L >> 7, colb = L & 127;
      const float* src = A + (size_t)(m0 + row) * 256 + kk * 64 + (colb >> 1);
      float4v f0 = *(const float4v*)(src);
      float4v f1 = *(const float4v*)(src + 4);
      *(short8v*)(sa + row * 128 + (colb ^ ((row & 7) << 4))) = cvt8(f0, f1);
    }
    #pragma unroll
    for (int p = 0; p < 4; ++p) {
      int L = p * 4096 + w * 1024 + lane * 16;
      int row = L >> 7, colb = L & 127;
      int sw = colb ^ ((row & 7) << 4);
      async16(Wb + (size_t)(n0 + row) * 512 + kk * 128 + sw, sb + p * 4096 + w * 1024);
    }
    __syncthreads();
    #pragma unroll
    for (int ks = 0; ks < 2; ++ks) {
      short8v af[4], bfr[4];
      #pragma unroll
      for (int mf = 0; mf < 4; ++mf) {
        int r = wr * 64 + mf * 16 + ln15;
        af[mf] = *(const short8v*)(sa + r * 128 + ((ks * 64 + gq * 16) ^ ((r & 7) << 4)));
      }
      #pragma unroll
      for (int nf = 0; nf < 4; ++nf) {
        int r = wc * 64 + nf * 16 + ln15;
        bfr[nf] = *(const short8v*)(sb + r * 128 + ((ks * 64 + gq * 16) ^ ((r & 7) << 4)));
      }
      #pragma unroll
      for (int mf = 0; mf < 4; ++mf)
        #pragma unroll
        for (int nf = 0; nf < 4; ++nf)
          acc[mf][nf] = mfma32(af[mf], bfr[nf], acc[mf][nf]);
    }
    __syncthreads();
  }
  #pragma unroll
  for (int nf = 0; nf < 4; ++nf) {
    int col = n0 + wc * 64 + nf * 16 + ln15;  // 0..511
    const bool isK = col < 256;
    const int c2 = col & 255;
    u16* outp = isK ? Kout : Vout;
    float bb = isK ? bk[c2] : bv[c2];
    const size_t hb = (size_t)(c2 >> 5) * S32E;
    const int d = c2 & 31;
    #pragma unroll
    for (int mf = 0; mf < 4; ++mf) {
      int rb = m0 + wr * 64 + mf * 16 + 4 * gq;
      #pragma unroll
      for (int j = 0; j < 4; ++j)
        outp[hb + (size_t)(rb + j) * 32 + d] = f2bf(acc[mf][nf][j] + bb);
    }
  }
}

// ---- Wo GEMM + residual + LN1 fused: x = LN1(q_in + ctx@Wo + bo), bf16 out ----
__global__ __launch_bounds__(256, 2)
void gemm_wo_ln(const u16* __restrict__ A, const u16* __restrict__ Wt,
                const float* __restrict__ bias, const float* __restrict__ resid,
                const float* __restrict__ lng, const float* __restrict__ lnb,
                u16* __restrict__ xout) {
  __shared__ alignas(16) char sa[16384];   // A tile [128][128B], XOR-swizzled
  __shared__ alignas(16) char sb[32768];   // B tile [256][128B], XOR-swizzled
  __shared__ float red[512];               // [128 rows][2 wc][2 {sum,sq}]
  const int tid = threadIdx.x;
  const int w = tid >> 6, lane = tid & 63;
  const int ln15 = lane & 15, gq = lane >> 4;
  const int wr = w >> 1, wc = w & 1;
  const int m0 = blockIdx.x * 128;
  const char* Ab = (const char*)A;
  const char* Wb = (const char*)Wt;

  float4v acc[4][8] = {};
  for (int kk = 0; kk < 4; ++kk) {
    #pragma unroll
    for (int p = 0; p < 4; ++p) {
      int L = p * 4096 + tid * 16;
      int row = L >> 7, colb = L & 127;
      int sw = colb ^ ((row & 7) << 4);
      int b = kk * 128 + sw;
      async16(Ab + (size_t)(b >> 6) * S64B + (size_t)(m0 + row) * 64 + (b & 63),
              sa + L);
    }
    #pragma unroll
    for (int p = 0; p < 8; ++p) {
      int L = p * 4096 + tid * 16;
      int row = L >> 7, colb = L & 127;
      int sw = colb ^ ((row & 7) << 4);
      async16(Wb + (size_t)row * 512 + kk * 128 + sw, sb + L);
    }
    __syncthreads();
    #pragma unroll
    for (int ks = 0; ks < 2; ++ks) {
      short8v af[4], bfr[8];
      #pragma unroll
      for (int mf = 0; mf < 4; ++mf) {
        int r = wr * 64 + mf * 16 + ln15;
        af[mf] = *(const short8v*)(sa + r * 128 + ((ks * 64 + gq * 16) ^ ((r & 7) << 4)));
      }
      #pragma unroll
      for (int nf = 0; nf < 8; ++nf) {
        int r = wc * 128 + nf * 16 + ln15;
        bfr[nf] = *(const short8v*)(sb + r * 128 + ((ks * 64 + gq * 16) ^ ((r & 7) << 4)));
      }
      #pragma unroll
      for (int mf = 0; mf < 4; ++mf)
        #pragma unroll
        for (int nf = 0; nf < 8; ++nf)
          acc[mf][nf] = mfma32(af[mf], bfr[nf], acc[mf][nf]);
    }
    __syncthreads();
  }

  #pragma unroll
  for (int mf = 0; mf < 4; ++mf)
    #pragma unroll
    for (int j = 0; j < 4; ++j) {
      int lr = wr * 64 + mf * 16 + 4 * gq + j;   // local row 0..127
      int r2 = m0 + lr;
      float sum = 0.f, sq = 0.f;
      #pragma unroll
      for (int nf = 0; nf < 8; ++nf) {
        int col = wc * 128 + nf * 16 + ln15;
        float v = acc[mf][nf][j] + bias[col] + resid[(size_t)r2 * 256 + col];
        acc[mf][nf][j] = v;
        sum += v;
        sq += v * v;
      }
      #pragma unroll
      for (int m = 1; m <= 8; m <<= 1) {
        sum += __shfl_xor(sum, m);
        sq += __shfl_xor(sq, m);
      }
      if (ln15 == 0) {
        red[lr * 4 + wc * 2] = sum;
        red[lr * 4 + wc * 2 + 1] = sq;
      }
    }
  __syncthreads();

  #pragma unroll
  for (int mf = 0; mf < 4; ++mf)
    #pragma unroll
    for (int j = 0; j < 4; ++j) {
      int lr = wr * 64 + mf * 16 + 4 * gq + j;
      int r2 = m0 + lr;
      float S = red[lr * 4] + red[lr * 4 + 2];
      float S2 = red[lr * 4 + 1] + red[lr * 4 + 3];
      float mu = S * (1.f / 256.f);
      float var = S2 * (1.f / 256.f) - mu * mu;
      float rstd = rsqrtf(var + 1e-5f);
      #pragma unroll
      for (int nf = 0; nf < 8; ++nf) {
        int col = wc * 128 + nf * 16 + ln15;
        float o = (acc[mf][nf][j] - mu) * rstd * lng[col] + lnb[col];
        xout[(size_t)r2 * 256 + col] = f2bf(o);
      }
    }
}

// ---------------- windowed attention v2 (R12-proven) + setprio hint ----------------
__global__ __launch_bounds__(256, 2)
void attn_v2(const u16* __restrict__ Qg, const u16* __restrict__ Kg,
             const u16* __restrict__ Vg, u16* __restrict__ ctx) {
  __shared__ alignas(16) char ks[256 * 80];
  __shared__ alignas(16) char vs[256 * 80];
  const int bw = blockIdx.x;
  const int win = bw >> 3, head = bw & 7;
  const int tid = threadIdx.x;
  const int w = tid >> 6, lane = tid & 63;
  const int ln15 = lane & 15, gq = lane >> 4;
  const int tok0 = win << 8;
  const u16* Qh = Qg + head * S32E + (size_t)tok0 * 32;
  const u16* Kh = Kg + head * S32E + (size_t)tok0 * 32;
  const u16* Vh = Vg + head * S32E + (size_t)tok0 * 32;
  u16* Ch = ctx + head * S32E + (size_t)tok0 * 32;

  #pragma unroll
  for (int i = 0; i < 4; ++i) {
    int L = i * 4096 + tid * 16;
    int row = L >> 6, colb = L & 63;
    short8v kv0 = *(const short8v*)((const char*)Kh + L);
    short8v vv0 = *(const short8v*)((const char*)Vh + L);
    *(short8v*)(ks + row * 80 + colb) = kv0;
    *(short8v*)(vs + row * 80 + colb) = vv0;
  }
  __syncthreads();

  const float KSC = (float)(1.4426950408889634 / 5.656854249492381);  // log2e/sqrt(32)

  for (int pass = 0; pass < 2; ++pass) {
    const int q0 = w * 64 + pass * 32;

    short8v qf[2];
    #pragma unroll
    for (int qi = 0; qi < 2; ++qi)
      qf[qi] = *(const short8v*)(Qh + (size_t)(q0 + qi * 16 + ln15) * 32 + gq * 8);

    float4v s[16][2];
    __builtin_amdgcn_s_setprio(1);
    #pragma unroll
    for (int kf = 0; kf < 16; ++kf) {
      short8v kfr = *(const short8v*)(ks + (16 * kf + ln15) * 80 + gq * 16);
      float4v z = {0.f, 0.f, 0.f, 0.f};
      s[kf][0] = mfma32(kfr, qf[0], z);
      s[kf][1] = mfma32(kfr, qf[1], z);
    }
    __builtin_amdgcn_s_setprio(0);

    float rs[2];
    #pragma unroll
    for (int qi = 0; qi < 2; ++qi) {
      float mx = -1e30f;
      #pragma unroll
      for (int kf = 0; kf < 16; ++kf)
        #pragma unroll
        for (int j = 0; j < 4; ++j) mx = fmaxf(mx, s[kf][qi][j]);
      mx = fmaxf(mx, __shfl_xor(mx, 16));
      mx = fmaxf(mx, __shfl_xor(mx, 32));
      float mk = mx * KSC;
      float sum = 0.f;
      #pragma unroll
      for (int kf = 0; kf < 16; ++kf)
        #pragma unroll
        for (int j = 0; j < 4; ++j) {
          float p = exp2f(fmaf(s[kf][qi][j], KSC, -mk));
          s[kf][qi][j] = p;
          sum += p;
        }
      sum += __shfl_xor(sum, 16);
      sum += __shfl_xor(sum, 32);
      rs[qi] = 1.0f / sum;
    }

    float4v cacc[2][2] = {};  // [df][qi]
    __builtin_amdgcn_s_setprio(1);
    #pragma unroll
    for (int kss = 0; kss < 16; ++kss) {
      short4v pb[2];
      pb[0] = cvt4(s[kss][0]);
      pb[1] = cvt4(s[kss][1]);
      #pragma unroll
      for (int df = 0; df < 2; ++df) {
        const char* vb = vs + (size_t)(16 * kss + 4 * gq) * 80 + (df * 16 + ln15) * 2;
        short4v va;
        va[0] = *(const short*)(vb);
        va[1] = *(const short*)(vb + 80);
        va[2] = *(const short*)(vb + 160);
        va[3] = *(const short*)(vb + 240);
        cacc[df][0] = mfma16(va, pb[0], cacc[df][0]);
        cacc[df][1] = mfma16(va, pb[1], cacc[df][1]);
      }
    }
    __builtin_amdgcn_s_setprio(0);

    #pragma unroll
    for (int qi = 0; qi < 2; ++qi)
      #pragma unroll
      for (int df = 0; df < 2; ++df) {
        short4v o;
        #pragma unroll
        for (int j = 0; j < 4; ++j) o[j] = (short)f2bf(cacc[df][qi][j] * rs[qi]);
        *(short4v*)(Ch + (size_t)(q0 + qi * 16 + ln15) * 32 + df * 16 + 4 * gq) = o;
      }
  }
}

// ---------------- fused FFN v6 + residual + LN2 (R12-proven, verbatim) ----------------
__global__ __launch_bounds__(512, 2)
void ffn_v6(const u16* __restrict__ X, const u16* __restrict__ W1t,
            const u16* __restrict__ W2tp, const float* __restrict__ b1,
            const float* __restrict__ b2, const float* __restrict__ g2,
            const float* __restrict__ be2, float* __restrict__ out) {
  __shared__ alignas(16) char w1c[2][16384];   // [32 f][512B k], XOR-swizzled
  __shared__ alignas(16) char w2c[2][20480];   // [256 n][80B] (64B data + 16 pad)
  __shared__ alignas(16) float b1s[1024];
  const int tid = threadIdx.x;  // 0..511
  const int w = tid >> 6, lane = tid & 63;
  const int ln15 = lane & 15, gq = lane >> 4;
  const int m0 = blockIdx.x * 256;
  const int wrow0 = m0 + w * 32;

  b1s[tid] = b1[tid];
  b1s[tid + 512] = b1[tid + 512];

  short8v xr[2][8];
  #pragma unroll
  for (int ct = 0; ct < 2; ++ct)
    #pragma unroll
    for (int kc = 0; kc < 8; ++kc)
      xr[ct][kc] = *(const short8v*)(X + (size_t)(wrow0 + ct * 16 + ln15) * 256 + kc * 32 + gq * 8);

  float4v ff[2][16] = {};
  short8v w2r[2];

  const char* W1b = (const char*)W1t;
  const char* W2b = (const char*)W2tp;

  #define STAGE_W1(buf, c)                                                     \
    {                                                                          \
      _Pragma("unroll")                                                        \
      for (int p = 0; p < 2; ++p) {                                            \
        int L = p * 8192 + tid * 16;                                           \
        int r = L >> 9, colb = L & 511;                                        \
        async16(W1b + (size_t)((c) * 32 + r) * 512 + (colb ^ ((r & 7) << 4)),  \
                w1c[buf] + L);                                                 \
      }                                                                        \
    }
  #define LOAD_W2(c)                                                           \
    {                                                                          \
      _Pragma("unroll")                                                        \
      for (int p = 0; p < 2; ++p) {                                            \
        int idx = p * 8192 + tid * 16;                                         \
        int n = idx >> 6, off = idx & 63;                                      \
        w2r[p] = *(const short8v*)(W2b + (size_t)n * 2048 + (c) * 64 + off);   \
      }                                                                        \
    }
  #define WRITE_W2(buf)                                                        \
    {                                                                          \
      _Pragma("unroll")                                                        \
      for (int p = 0; p < 2; ++p) {                                            \
        int idx = p * 8192 + tid * 16;                                         \
        int n = idx >> 6, off = idx & 63;                                      \
        *(short8v*)(w2c[buf] + n * 80 + off) = w2r[p];                         \
      }                                                                        \
    }

  STAGE_W1(0, 0);
  LOAD_W2(0);
  WRITE_W2(0);
  __syncthreads();

  #pragma unroll 2
  for (int c = 0; c < 32; ++c) {
    const int buf = c & 1;
    if (c < 31) {
      STAGE_W1(buf ^ 1, c + 1);
      LOAD_W2(c + 1);
    }

    float4v g1[2][2] = {};
    #pragma unroll
    for (int kc = 0; kc < 8; ++kc) {
      #pragma unroll
      for (int ft = 0; ft < 2; ++ft) {
        int r = ft * 16 + ln15;
        short8v a = *(const short8v*)(w1c[buf] + r * 512 +
                                      ((kc * 64 + gq * 16) ^ ((r & 7) << 4)));
        g1[0][ft] = mfma32(a, xr[0][kc], g1[0][ft]);
        g1[1][ft] = mfma32(a, xr[1][kc], g1[1][ft]);
      }
    }
    short8v pa8[2];
    #pragma unroll
    for (int ft = 0; ft < 2; ++ft) {
      float4v bv4 = *(const float4v*)(b1s + c * 32 + ft * 16 + 4 * gq);
      #pragma unroll
      for (int ct = 0; ct < 2; ++ct)
        #pragma unroll
        for (int j = 0; j < 4; ++j) {
          float v = g1[ct][ft][j] + bv4[j];
          v = v > 0.f ? v : 0.f;
          pa8[ct][ft * 4 + j] = (short)f2bf(v);
        }
    }
    #pragma unroll
    for (int nt = 0; nt < 16; ++nt) {
      short8v wb = *(const short8v*)(w2c[buf] + (nt * 16 + ln15) * 80 + gq * 16);
      ff[0][nt] = mfma32(pa8[0], wb, ff[0][nt]);
      ff[1][nt] = mfma32(pa8[1], wb, ff[1][nt]);
    }

    if (c < 31) WRITE_W2(buf ^ 1);
    __syncthreads();
  }

  #pragma unroll
  for (int ct = 0; ct < 2; ++ct)
    #pragma unroll
    for (int j = 0; j < 4; ++j) {
      int r2 = wrow0 + ct * 16 + 4 * gq + j;
      float sum = 0.f, sq = 0.f;
      float vv[16];
      #pragma unroll
      for (int nt = 0; nt < 16; ++nt) {
        int col = nt * 16 + ln15;
        float xv = bf2f(X[(size_t)r2 * 256 + col]);
        float v = ff[ct][nt][j] + b2[col] + xv;
        vv[nt] = v;
        sum += v;
        sq += v * v;
      }
      #pragma unroll
      for (int m = 1; m <= 8; m <<= 1) {
        sum += __shfl_xor(sum, m);
        sq += __shfl_xor(sq, m);
      }
      float mu = sum * (1.f / 256.f);
      float var = sq * (1.f / 256.f) - mu * mu;
      float rstd = rsqrtf(var + 1e-5f);
      #pragma unroll
      for (int nt = 0; nt < 16; ++nt) {
        int col = nt * 16 + ln15;
        out[(size_t)r2 * 256 + col] = (vv[nt] - mu) * rstd * g2[col] + be2[col];
      }
    }
  #undef STAGE_W1
  #undef LOAD_W2
  #undef WRITE_W2
}

extern "C" void kernel_launch(void* const* d_in, const int* in_sizes, int n_in,
                              void* d_out, int out_size, void* d_ws, size_t ws_size,
                              hipStream_t stream) {
  (void)in_sizes; (void)n_in; (void)out_size;
  const float* query = (const float*)d_in[0];
  const float* kv    = (const float*)d_in[1];
  const float* Wqm = (const float*)d_in[2];  const float* bq = (const float*)d_in[3];
  const float* Wkm = (const float*)d_in[4];  const float* bk = (const float*)d_in[5];
  const float* Wvm = (const float*)d_in[6];  const float* bv = (const float*)d_in[7];
  const float* Wom = (const float*)d_in[8];  const float* bo = (const float*)d_in[9];
  const float* ln1g = (const float*)d_in[10]; const float* ln1b = (const float*)d_in[11];
  const float* W1m = (const float*)d_in[12]; const float* b1 = (const float*)d_in[13];
  const float* W2m = (const float*)d_in[14]; const float* b2 = (const float*)d_in[15];
  const float* ln2g = (const float*)d_in[16]; const float* ln2b = (const float*)d_in[17];
  float* out = (float*)d_out;

  char* ws = (char*)d_ws;
  const size_t MB = 1ull << 20;
  if (ws_size < 130 * MB) return;

  // workspace layout (all bf16); Q/K/V/ctx are head-major [8][65536][32]
  u16* Vw   = (u16*)(ws);            // [0,32M)
  u16* ctxw = (u16*)(ws + 32 * MB);  // [32,64M)
  u16* Qw   = (u16*)(ws + 64 * MB);  // dead after attn
  u16* xw   = (u16*)(ws + 64 * MB);  // aliases Qw
  u16* Kw   = (u16*)(ws + 96 * MB);
  char* wb = ws + 128 * MB;
  u16* Wqt = (u16*)(wb);
  u16* Wkt = (u16*)(wb + 131072);
  u16* Wvt = (u16*)(wb + 262144);
  u16* Wot = (u16*)(wb + 393216);
  u16* W1t = (u16*)(wb + 524288);
  u16* W2t = (u16*)(wb + 1048576);

  cvt_wT<<<dim3(64, 6), 256, 0, stream>>>(Wqm, Wkm, Wvm, Wom, W1m, W2m,
                                          Wqt, Wkt, Wvt, Wot, W1t, W2t);
  gemm_q<<<dim3(512, 2), 256, 0, stream>>>(query, Wqt, bq, Qw);
  gemm_kv<<<dim3(512, 4), 256, 0, stream>>>(kv, Wkt, bk, bv, Kw, Vw);
  attn_v2<<<dim3(2048), 256, 0, stream>>>(Qw, Kw, Vw, ctxw);
  gemm_wo_ln<<<dim3(512), 256, 0, stream>>>(ctxw, Wot, bo, query, ln1g, ln1b, xw);
  ffn_v6<<<dim3(256), 512, 0, stream>>>(xw, W1t, W2t, b1, b2, ln2g, ln2b, out);
}

// Round 16
// 281.015 us; speedup vs baseline: 1.1847x; 1.0257x over previous
//
#include <hip/hip_runtime.h>

#define DEV __device__ __forceinline__

typedef short short4v __attribute__((ext_vector_type(4)));
typedef short short8v __attribute__((ext_vector_type(8)));
typedef float float4v __attribute__((ext_vector_type(4)));
typedef unsigned short u16;

#define S32E ((size_t)65536 * 32)   // head stride, elements (u16)
#define S64B ((size_t)65536 * 64)   // head stride, bytes

DEV unsigned short f2bf(float f) {
  unsigned u = __builtin_bit_cast(unsigned, f);
  u += 0x7fffu + ((u >> 16) & 1u);
  return (unsigned short)(u >> 16);
}
DEV float bf2f(unsigned short h) {
  unsigned u = ((unsigned)h) << 16;
  return __builtin_bit_cast(float, u);
}
DEV float4v mfma32(short8v a, short8v b, float4v c) {
  return __builtin_amdgcn_mfma_f32_16x16x32_bf16(a, b, c, 0, 0, 0);
}
DEV float4v mfma16(short4v a, short4v b, float4v c) {
  return __builtin_amdgcn_mfma_f32_16x16x16bf16_1k(a, b, c, 0, 0, 0);
}
DEV void async16(const void* g, void* l) {
  __builtin_amdgcn_global_load_lds(
      (const __attribute__((address_space(1))) unsigned*)g,
      (__attribute__((address_space(3))) unsigned*)l, 16, 0, 0);
}
DEV short4v cvt4(float4v v) {
  short4v r;
  r[0] = (short)f2bf(v[0]); r[1] = (short)f2bf(v[1]);
  r[2] = (short)f2bf(v[2]); r[3] = (short)f2bf(v[3]);
  return r;
}
DEV short8v cvt8(float4v a, float4v b) {
  short8v o;
  o[0] = (short)f2bf(a[0]); o[1] = (short)f2bf(a[1]);
  o[2] = (short)f2bf(a[2]); o[3] = (short)f2bf(a[3]);
  o[4] = (short)f2bf(b[0]); o[5] = (short)f2bf(b[1]);
  o[6] = (short)f2bf(b[2]); o[7] = (short)f2bf(b[3]);
  return o;
}

// ------------- weight convert + transpose (LDS-tiled, coalesced) -------------
__global__ __launch_bounds__(256)
void cvt_wT(const float* Wq, const float* Wk, const float* Wv, const float* Wo,
            const float* W1, const float* W2,
            u16* Wqt, u16* Wkt, u16* Wvt, u16* Wot, u16* W1t, u16* W2t) {
  __shared__ float ld[64 * 69];
  const float* src; u16* dst; int R, C; bool permk = false;
  switch (blockIdx.y) {
    case 0: src = Wq; dst = Wqt; R = 256;  C = 256;  break;
    case 1: src = Wk; dst = Wkt; R = 256;  C = 256;  break;
    case 2: src = Wv; dst = Wvt; R = 256;  C = 256;  break;
    case 3: src = Wo; dst = Wot; R = 256;  C = 256;  break;
    case 4: src = W1; dst = W1t; R = 256;  C = 1024; break;
    default: src = W2; dst = W2t; R = 1024; C = 256; permk = true; break;
  }
  const int ntile = (R >> 6) * (C >> 6);
  if ((int)blockIdx.x >= ntile) return;
  const int tf = blockIdx.x % (R >> 6);
  const int tn = blockIdx.x / (R >> 6);
  const int r0 = tf << 6, c0 = tn << 6;
  const int tid = threadIdx.x;
  {
    int lr = tid >> 4, lc = (tid & 15) << 2;
    #pragma unroll
    for (int ps = 0; ps < 4; ++ps) {
      int r = ps * 16 + lr;
      float4v v = *(const float4v*)(src + (size_t)(r0 + r) * C + c0 + lc);
      #pragma unroll
      for (int e = 0; e < 4; ++e) ld[r * 69 + lc + e] = v[e];
    }
  }
  __syncthreads();
  {
    int p8 = (tid & 7) << 3;
    #pragma unroll
    for (int ps = 0; ps < 2; ++ps) {
      int n = ps * 32 + (tid >> 3);
      short8v o;
      #pragma unroll
      for (int e = 0; e < 8; ++e) {
        int p = p8 + e;
        int fl = p;
        if (permk) {
          int m = p & 31;
          fl = (p & 32) + 16 * ((m >> 2) & 1) + 4 * (m >> 3) + (m & 3);
        }
        o[e] = (short)f2bf(ld[fl * 69 + n]);
      }
      *(short8v*)(dst + (size_t)(c0 + n) * R + r0 + p8) = o;
    }
  }
}

// ---------------- Q projection GEMM: out = A_f32 @ Wt^T + bias, head-major out ----
__global__ __launch_bounds__(256, 2)
void gemm_q(const float* __restrict__ A, const u16* __restrict__ Wt,
            const float* __restrict__ bias, u16* __restrict__ out) {
  __shared__ alignas(16) char sm[32768];
  char* sa = sm;
  char* sb = sm + 16384;
  const int tid = threadIdx.x;
  const int w = tid >> 6, lane = tid & 63;
  const int ln15 = lane & 15, gq = lane >> 4;
  const int wr = w >> 1, wc = w & 1;
  const int m0 = blockIdx.x * 128, n0 = blockIdx.y * 128;
  const char* Wb = (const char*)Wt;

  float4v acc[4][4] = {};
  for (int kk = 0; kk < 4; ++kk) {
    #pragma unroll
    for (int p = 0; p < 4; ++p) {
      int L = p * 4096 + w * 1024 + lane * 16;
      int row = L >> 7, colb = L & 127;
      const float* src = A + (size_t)(m0 + row) * 256 + kk * 64 + (colb >> 1);
      float4v f0 = *(const float4v*)(src);
      float4v f1 = *(const float4v*)(src + 4);
      *(short8v*)(sa + row * 128 + (colb ^ ((row & 7) << 4))) = cvt8(f0, f1);
    }
    #pragma unroll
    for (int p = 0; p < 4; ++p) {
      int L = p * 4096 + w * 1024 + lane * 16;
      int row = L >> 7, colb = L & 127;
      int sw = colb ^ ((row & 7) << 4);
      async16(Wb + (size_t)(n0 + row) * 512 + kk * 128 + sw, sb + p * 4096 + w * 1024);
    }
    __syncthreads();
    #pragma unroll
    for (int ks = 0; ks < 2; ++ks) {
      short8v af[4], bfr[4];
      #pragma unroll
      for (int mf = 0; mf < 4; ++mf) {
        int r = wr * 64 + mf * 16 + ln15;
        af[mf] = *(const short8v*)(sa + r * 128 + ((ks * 64 + gq * 16) ^ ((r & 7) << 4)));
      }
      #pragma unroll
      for (int nf = 0; nf < 4; ++nf) {
        int r = wc * 64 + nf * 16 + ln15;
        bfr[nf] = *(const short8v*)(sb + r * 128 + ((ks * 64 + gq * 16) ^ ((r & 7) << 4)));
      }
      #pragma unroll
      for (int mf = 0; mf < 4; ++mf)
        #pragma unroll
        for (int nf = 0; nf < 4; ++nf)
          acc[mf][nf] = mfma32(af[mf], bfr[nf], acc[mf][nf]);
    }
    __syncthreads();
  }
  #pragma unroll
  for (int nf = 0; nf < 4; ++nf) {
    int col = n0 + wc * 64 + nf * 16 + ln15;
    float bb = bias[col];
    #pragma unroll
    for (int mf = 0; mf < 4; ++mf) {
      int rb = m0 + wr * 64 + mf * 16 + 4 * gq;
      #pragma unroll
      for (int j = 0; j < 4; ++j) {
        float v = acc[mf][nf][j] + bb;
        out[(size_t)(col >> 5) * S32E + (size_t)(rb + j) * 32 + (col & 31)] = f2bf(v);
      }
    }
  }
}

// ---------------- merged K/V projection GEMM (f32 A, head-major outputs) ----------------
__global__ __launch_bounds__(256, 2)
void gemm_kv(const float* __restrict__ A, const u16* __restrict__ Wt,
             const float* __restrict__ bk, const float* __restrict__ bv,
             u16* __restrict__ Kout, u16* __restrict__ Vout) {
  __shared__ alignas(16) char sm[32768];
  char* sa = sm;
  char* sb = sm + 16384;
  const int tid = threadIdx.x;
  const int w = tid >> 6, lane = tid & 63;
  const int ln15 = lane & 15, gq = lane >> 4;
  const int wr = w >> 1, wc = w & 1;
  const int m0 = blockIdx.x * 128, n0 = blockIdx.y * 128;
  const char* Wb = (const char*)Wt;

  float4v acc[4][4] = {};
  for (int kk = 0; kk < 4; ++kk) {
    #pragma unroll
    for (int p = 0; p < 4; ++p) {
      int L = p * 4096 + w * 1024 + lane * 16;
      int row = L >> 7, colb = L & 127;
      const float* src = A + (size_t)(m0 + row) * 256 + kk * 64 + (colb >> 1);
      float4v f0 = *(const float4v*)(src);
      float4v f1 = *(const float4v*)(src + 4);
      *(short8v*)(sa + row * 128 + (colb ^ ((row & 7) << 4))) = cvt8(f0, f1);
    }
    #pragma unroll
    for (int p = 0; p < 4; ++p) {
      int L = p * 4096 + w * 1024 + lane * 16;
      int row = L >> 7, colb = L & 127;
      int sw = colb ^ ((row & 7) << 4);
      async16(Wb + (size_t)(n0 + row) * 512 + kk * 128 + sw, sb + p * 4096 + w * 1024);
    }
    __syncthreads();
    #pragma unroll
    for (int ks = 0; ks < 2; ++ks) {
      short8v af[4], bfr[4];
      #pragma unroll
      for (int mf = 0; mf < 4; ++mf) {
        int r = wr * 64 + mf * 16 + ln15;
        af[mf] = *(const short8v*)(sa + r * 128 + ((ks * 64 + gq * 16) ^ ((r & 7) << 4)));
      }
      #pragma unroll
      for (int nf = 0; nf < 4; ++nf) {
        int r = wc * 64 + nf * 16 + ln15;
        bfr[nf] = *(const short8v*)(sb + r * 128 + ((ks * 64 + gq * 16) ^ ((r & 7) << 4)));
      }
      #pragma unroll
      for (int mf = 0; mf < 4; ++mf)
        #pragma unroll
        for (int nf = 0; nf < 4; ++nf)
          acc[mf][nf] = mfma32(af[mf], bfr[nf], acc[mf][nf]);
    }
    __syncthreads();
  }
  #pragma unroll
  for (int nf = 0; nf < 4; ++nf) {
    int col = n0 + wc * 64 + nf * 16 + ln15;  // 0..511
    const bool isK = col < 256;
    const int c2 = col & 255;
    u16* outp = isK ? Kout : Vout;
    float bb = isK ? bk[c2] : bv[c2];
    const size_t hb = (size_t)(c2 >> 5) * S32E;
    const int d = c2 & 31;
    #pragma unroll
    for (int mf = 0; mf < 4; ++mf) {
      int rb = m0 + wr * 64 + mf * 16 + 4 * gq;
      #pragma unroll
      for (int j = 0; j < 4; ++j)
        outp[hb + (size_t)(rb + j) * 32 + d] = f2bf(acc[mf][nf][j] + bb);
    }
  }
}

// ---- Wo GEMM + residual + LN1 fused: x = LN1(q_in + ctx@Wo + bo), bf16 out ----
__global__ __launch_bounds__(256, 2)
void gemm_wo_ln(const u16* __restrict__ A, const u16* __restrict__ Wt,
                const float* __restrict__ bias, const float* __restrict__ resid,
                const float* __restrict__ lng, const float* __restrict__ lnb,
                u16* __restrict__ xout) {
  __shared__ alignas(16) char sa[16384];   // A tile [128][128B], XOR-swizzled
  __shared__ alignas(16) char sb[32768];   // B tile [256][128B], XOR-swizzled
  __shared__ float red[512];               // [128 rows][2 wc][2 {sum,sq}]
  const int tid = threadIdx.x;
  const int w = tid >> 6, lane = tid & 63;
  const int ln15 = lane & 15, gq = lane >> 4;
  const int wr = w >> 1, wc = w & 1;
  const int m0 = blockIdx.x * 128;
  const char* Ab = (const char*)A;
  const char* Wb = (const char*)Wt;

  float4v acc[4][8] = {};
  for (int kk = 0; kk < 4; ++kk) {
    #pragma unroll
    for (int p = 0; p < 4; ++p) {
      int L = p * 4096 + tid * 16;
      int row = L >> 7, colb = L & 127;
      int sw = colb ^ ((row & 7) << 4);
      int b = kk * 128 + sw;
      async16(Ab + (size_t)(b >> 6) * S64B + (size_t)(m0 + row) * 64 + (b & 63),
              sa + L);
    }
    #pragma unroll
    for (int p = 0; p < 8; ++p) {
      int L = p * 4096 + tid * 16;
      int row = L >> 7, colb = L & 127;
      int sw = colb ^ ((row & 7) << 4);
      async16(Wb + (size_t)row * 512 + kk * 128 + sw, sb + L);
    }
    __syncthreads();
    #pragma unroll
    for (int ks = 0; ks < 2; ++ks) {
      short8v af[4], bfr[8];
      #pragma unroll
      for (int mf = 0; mf < 4; ++mf) {
        int r = wr * 64 + mf * 16 + ln15;
        af[mf] = *(const short8v*)(sa + r * 128 + ((ks * 64 + gq * 16) ^ ((r & 7) << 4)));
      }
      #pragma unroll
      for (int nf = 0; nf < 8; ++nf) {
        int r = wc * 128 + nf * 16 + ln15;
        bfr[nf] = *(const short8v*)(sb + r * 128 + ((ks * 64 + gq * 16) ^ ((r & 7) << 4)));
      }
      #pragma unroll
      for (int mf = 0; mf < 4; ++mf)
        #pragma unroll
        for (int nf = 0; nf < 8; ++nf)
          acc[mf][nf] = mfma32(af[mf], bfr[nf], acc[mf][nf]);
    }
    __syncthreads();
  }

  #pragma unroll
  for (int mf = 0; mf < 4; ++mf)
    #pragma unroll
    for (int j = 0; j < 4; ++j) {
      int lr = wr * 64 + mf * 16 + 4 * gq + j;   // local row 0..127
      int r2 = m0 + lr;
      float sum = 0.f, sq = 0.f;
      #pragma unroll
      for (int nf = 0; nf < 8; ++nf) {
        int col = wc * 128 + nf * 16 + ln15;
        float v = acc[mf][nf][j] + bias[col] + resid[(size_t)r2 * 256 + col];
        acc[mf][nf][j] = v;
        sum += v;
        sq += v * v;
      }
      #pragma unroll
      for (int m = 1; m <= 8; m <<= 1) {
        sum += __shfl_xor(sum, m);
        sq += __shfl_xor(sq, m);
      }
      if (ln15 == 0) {
        red[lr * 4 + wc * 2] = sum;
        red[lr * 4 + wc * 2 + 1] = sq;
      }
    }
  __syncthreads();

  #pragma unroll
  for (int mf = 0; mf < 4; ++mf)
    #pragma unroll
    for (int j = 0; j < 4; ++j) {
      int lr = wr * 64 + mf * 16 + 4 * gq + j;
      int r2 = m0 + lr;
      float S = red[lr * 4] + red[lr * 4 + 2];
      float S2 = red[lr * 4 + 1] + red[lr * 4 + 3];
      float mu = S * (1.f / 256.f);
      float var = S2 * (1.f / 256.f) - mu * mu;
      float rstd = rsqrtf(var + 1e-5f);
      #pragma unroll
      for (int nf = 0; nf < 8; ++nf) {
        int col = wc * 128 + nf * 16 + ln15;
        float o = (acc[mf][nf][j] - mu) * rstd * lng[col] + lnb[col];
        xout[(size_t)r2 * 256 + col] = f2bf(o);
      }
    }
}

// ---------------- windowed attention v2 (R12-proven, verbatim) ----------------
__global__ __launch_bounds__(256, 2)
void attn_v2(const u16* __restrict__ Qg, const u16* __restrict__ Kg,
             const u16* __restrict__ Vg, u16* __restrict__ ctx) {
  __shared__ alignas(16) char ks[256 * 80];
  __shared__ alignas(16) char vs[256 * 80];
  const int bw = blockIdx.x;
  const int win = bw >> 3, head = bw & 7;
  const int tid = threadIdx.x;
  const int w = tid >> 6, lane = tid & 63;
  const int ln15 = lane & 15, gq = lane >> 4;
  const int tok0 = win << 8;
  const u16* Qh = Qg + head * S32E + (size_t)tok0 * 32;
  const u16* Kh = Kg + head * S32E + (size_t)tok0 * 32;
  const u16* Vh = Vg + head * S32E + (size_t)tok0 * 32;
  u16* Ch = ctx + head * S32E + (size_t)tok0 * 32;

  #pragma unroll
  for (int i = 0; i < 4; ++i) {
    int L = i * 4096 + tid * 16;
    int row = L >> 6, colb = L & 63;
    short8v kv0 = *(const short8v*)((const char*)Kh + L);
    short8v vv0 = *(const short8v*)((const char*)Vh + L);
    *(short8v*)(ks + row * 80 + colb) = kv0;
    *(short8v*)(vs + row * 80 + colb) = vv0;
  }
  __syncthreads();

  const float KSC = (float)(1.4426950408889634 / 5.656854249492381);  // log2e/sqrt(32)

  for (int pass = 0; pass < 2; ++pass) {
    const int q0 = w * 64 + pass * 32;

    short8v qf[2];
    #pragma unroll
    for (int qi = 0; qi < 2; ++qi)
      qf[qi] = *(const short8v*)(Qh + (size_t)(q0 + qi * 16 + ln15) * 32 + gq * 8);

    float4v s[16][2];
    #pragma unroll
    for (int kf = 0; kf < 16; ++kf) {
      short8v kfr = *(const short8v*)(ks + (16 * kf + ln15) * 80 + gq * 16);
      float4v z = {0.f, 0.f, 0.f, 0.f};
      s[kf][0] = mfma32(kfr, qf[0], z);
      s[kf][1] = mfma32(kfr, qf[1], z);
    }

    float rs[2];
    #pragma unroll
    for (int qi = 0; qi < 2; ++qi) {
      float mx = -1e30f;
      #pragma unroll
      for (int kf = 0; kf < 16; ++kf)
        #pragma unroll
        for (int j = 0; j < 4; ++j) mx = fmaxf(mx, s[kf][qi][j]);
      mx = fmaxf(mx, __shfl_xor(mx, 16));
      mx = fmaxf(mx, __shfl_xor(mx, 32));
      float mk = mx * KSC;
      float sum = 0.f;
      #pragma unroll
      for (int kf = 0; kf < 16; ++kf)
        #pragma unroll
        for (int j = 0; j < 4; ++j) {
          float p = exp2f(fmaf(s[kf][qi][j], KSC, -mk));
          s[kf][qi][j] = p;
          sum += p;
        }
      sum += __shfl_xor(sum, 16);
      sum += __shfl_xor(sum, 32);
      rs[qi] = 1.0f / sum;
    }

    float4v cacc[2][2] = {};  // [df][qi]
    #pragma unroll
    for (int kss = 0; kss < 16; ++kss) {
      short4v pb[2];
      pb[0] = cvt4(s[kss][0]);
      pb[1] = cvt4(s[kss][1]);
      #pragma unroll
      for (int df = 0; df < 2; ++df) {
        const char* vb = vs + (size_t)(16 * kss + 4 * gq) * 80 + (df * 16 + ln15) * 2;
        short4v va;
        va[0] = *(const short*)(vb);
        va[1] = *(const short*)(vb + 80);
        va[2] = *(const short*)(vb + 160);
        va[3] = *(const short*)(vb + 240);
        cacc[df][0] = mfma16(va, pb[0], cacc[df][0]);
        cacc[df][1] = mfma16(va, pb[1], cacc[df][1]);
      }
    }

    #pragma unroll
    for (int qi = 0; qi < 2; ++qi)
      #pragma unroll
      for (int df = 0; df < 2; ++df) {
        short4v o;
        #pragma unroll
        for (int j = 0; j < 4; ++j) o[j] = (short)f2bf(cacc[df][qi][j] * rs[qi]);
        *(short4v*)(Ch + (size_t)(q0 + qi * 16 + ln15) * 32 + df * 16 + 4 * gq) = o;
      }
  }
}

// ---------------- fused FFN v6 + residual + LN2 (R12-proven, verbatim) ----------------
__global__ __launch_bounds__(512, 2)
void ffn_v6(const u16* __restrict__ X, const u16* __restrict__ W1t,
            const u16* __restrict__ W2tp, const float* __restrict__ b1,
            const float* __restrict__ b2, const float* __restrict__ g2,
            const float* __restrict__ be2, float* __restrict__ out) {
  __shared__ alignas(16) char w1c[2][16384];   // [32 f][512B k], XOR-swizzled
  __shared__ alignas(16) char w2c[2][20480];   // [256 n][80B] (64B data + 16 pad)
  __shared__ alignas(16) float b1s[1024];
  const int tid = threadIdx.x;  // 0..511
  const int w = tid >> 6, lane = tid & 63;
  const int ln15 = lane & 15, gq = lane >> 4;
  const int m0 = blockIdx.x * 256;
  const int wrow0 = m0 + w * 32;

  b1s[tid] = b1[tid];
  b1s[tid + 512] = b1[tid + 512];

  short8v xr[2][8];
  #pragma unroll
  for (int ct = 0; ct < 2; ++ct)
    #pragma unroll
    for (int kc = 0; kc < 8; ++kc)
      xr[ct][kc] = *(const short8v*)(X + (size_t)(wrow0 + ct * 16 + ln15) * 256 + kc * 32 + gq * 8);

  float4v ff[2][16] = {};
  short8v w2r[2];

  const char* W1b = (const char*)W1t;
  const char* W2b = (const char*)W2tp;

  #define STAGE_W1(buf, c)                                                     \
    {                                                                          \
      _Pragma("unroll")                                                        \
      for (int p = 0; p < 2; ++p) {                                            \
        int L = p * 8192 + tid * 16;                                           \
        int r = L >> 9, colb = L & 511;                                        \
        async16(W1b + (size_t)((c) * 32 + r) * 512 + (colb ^ ((r & 7) << 4)),  \
                w1c[buf] + L);                                                 \
      }                                                                        \
    }
  #define LOAD_W2(c)                                                           \
    {                                                                          \
      _Pragma("unroll")                                                        \
      for (int p = 0; p < 2; ++p) {                                            \
        int idx = p * 8192 + tid * 16;                                         \
        int n = idx >> 6, off = idx & 63;                                      \
        w2r[p] = *(const short8v*)(W2b + (size_t)n * 2048 + (c) * 64 + off);   \
      }                                                                        \
    }
  #define WRITE_W2(buf)                                                        \
    {                                                                          \
      _Pragma("unroll")                                                        \
      for (int p = 0; p < 2; ++p) {                                            \
        int idx = p * 8192 + tid * 16;                                         \
        int n = idx >> 6, off = idx & 63;                                      \
        *(short8v*)(w2c[buf] + n * 80 + off) = w2r[p];                         \
      }                                                                        \
    }

  STAGE_W1(0, 0);
  LOAD_W2(0);
  WRITE_W2(0);
  __syncthreads();

  #pragma unroll 2
  for (int c = 0; c < 32; ++c) {
    const int buf = c & 1;
    if (c < 31) {
      STAGE_W1(buf ^ 1, c + 1);
      LOAD_W2(c + 1);
    }

    float4v g1[2][2] = {};
    #pragma unroll
    for (int kc = 0; kc < 8; ++kc) {
      #pragma unroll
      for (int ft = 0; ft < 2; ++ft) {
        int r = ft * 16 + ln15;
        short8v a = *(const short8v*)(w1c[buf] + r * 512 +
                                      ((kc * 64 + gq * 16) ^ ((r & 7) << 4)));
        g1[0][ft] = mfma32(a, xr[0][kc], g1[0][ft]);
        g1[1][ft] = mfma32(a, xr[1][kc], g1[1][ft]);
      }
    }
    short8v pa8[2];
    #pragma unroll
    for (int ft = 0; ft < 2; ++ft) {
      float4v bv4 = *(const float4v*)(b1s + c * 32 + ft * 16 + 4 * gq);
      #pragma unroll
      for (int ct = 0; ct < 2; ++ct)
        #pragma unroll
        for (int j = 0; j < 4; ++j) {
          float v = g1[ct][ft][j] + bv4[j];
          v = v > 0.f ? v : 0.f;
          pa8[ct][ft * 4 + j] = (short)f2bf(v);
        }
    }
    #pragma unroll
    for (int nt = 0; nt < 16; ++nt) {
      short8v wb = *(const short8v*)(w2c[buf] + (nt * 16 + ln15) * 80 + gq * 16);
      ff[0][nt] = mfma32(pa8[0], wb, ff[0][nt]);
      ff[1][nt] = mfma32(pa8[1], wb, ff[1][nt]);
    }

    if (c < 31) WRITE_W2(buf ^ 1);
    __syncthreads();
  }

  #pragma unroll
  for (int ct = 0; ct < 2; ++ct)
    #pragma unroll
    for (int j = 0; j < 4; ++j) {
      int r2 = wrow0 + ct * 16 + 4 * gq + j;
      float sum = 0.f, sq = 0.f;
      float vv[16];
      #pragma unroll
      for (int nt = 0; nt < 16; ++nt) {
        int col = nt * 16 + ln15;
        float xv = bf2f(X[(size_t)r2 * 256 + col]);
        float v = ff[ct][nt][j] + b2[col] + xv;
        vv[nt] = v;
        sum += v;
        sq += v * v;
      }
      #pragma unroll
      for (int m = 1; m <= 8; m <<= 1) {
        sum += __shfl_xor(sum, m);
        sq += __shfl_xor(sq, m);
      }
      float mu = sum * (1.f / 256.f);
      float var = sq * (1.f / 256.f) - mu * mu;
      float rstd = rsqrtf(var + 1e-5f);
      #pragma unroll
      for (int nt = 0; nt < 16; ++nt) {
        int col = nt * 16 + ln15;
        out[(size_t)r2 * 256 + col] = (vv[nt] - mu) * rstd * g2[col] + be2[col];
      }
    }
  #undef STAGE_W1
  #undef LOAD_W2
  #undef WRITE_W2
}

extern "C" void kernel_launch(void* const* d_in, const int* in_sizes, int n_in,
                              void* d_out, int out_size, void* d_ws, size_t ws_size,
                              hipStream_t stream) {
  (void)in_sizes; (void)n_in; (void)out_size;
  const float* query = (const float*)d_in[0];
  const float* kv    = (const float*)d_in[1];
  const float* Wqm = (const float*)d_in[2];  const float* bq = (const float*)d_in[3];
  const float* Wkm = (const float*)d_in[4];  const float* bk = (const float*)d_in[5];
  const float* Wvm = (const float*)d_in[6];  const float* bv = (const float*)d_in[7];
  const float* Wom = (const float*)d_in[8];  const float* bo = (const float*)d_in[9];
  const float* ln1g = (const float*)d_in[10]; const float* ln1b = (const float*)d_in[11];
  const float* W1m = (const float*)d_in[12]; const float* b1 = (const float*)d_in[13];
  const float* W2m = (const float*)d_in[14]; const float* b2 = (const float*)d_in[15];
  const float* ln2g = (const float*)d_in[16]; const float* ln2b = (const float*)d_in[17];
  float* out = (float*)d_out;

  char* ws = (char*)d_ws;
  const size_t MB = 1ull << 20;
  if (ws_size < 130 * MB) return;

  // workspace layout (all bf16); Q/K/V/ctx are head-major [8][65536][32]
  u16* Vw   = (u16*)(ws);            // [0,32M)
  u16* ctxw = (u16*)(ws + 32 * MB);  // [32,64M)
  u16* Qw   = (u16*)(ws + 64 * MB);  // dead after attn
  u16* xw   = (u16*)(ws + 64 * MB);  // aliases Qw
  u16* Kw   = (u16*)(ws + 96 * MB);
  char* wb = ws + 128 * MB;
  u16* Wqt = (u16*)(wb);
  u16* Wkt = (u16*)(wb + 131072);
  u16* Wvt = (u16*)(wb + 262144);
  u16* Wot = (u16*)(wb + 393216);
  u16* W1t = (u16*)(wb + 524288);
  u16* W2t = (u16*)(wb + 1048576);

  cvt_wT<<<dim3(64, 6), 256, 0, stream>>>(Wqm, Wkm, Wvm, Wom, W1m, W2m,
                                          Wqt, Wkt, Wvt, Wot, W1t, W2t);
  gemm_q<<<dim3(512, 2), 256, 0, stream>>>(query, Wqt, bq, Qw);
  gemm_kv<<<dim3(512, 4), 256, 0, stream>>>(kv, Wkt, bk, bv, Kw, Vw);
  attn_v2<<<dim3(2048), 256, 0, stream>>>(Qw, Kw, Vw, ctxw);
  gemm_wo_ln<<<dim3(512), 256, 0, stream>>>(ctxw, Wot, bo, query, ln1g, ln1b, xw);
  ffn_v6<<<dim3(256), 512, 0, stream>>>(xw, W1t, W2t, b1, b2, ln2g, ln2b, out);
}